// Round 1
// baseline (949.131 us; speedup 1.0000x reference)
//
#include <hip/hip_runtime.h>
#include <hip/hip_bf16.h>
#include <cstdint>
#include <cstddef>

// Problem constants (fixed by setup_inputs)
#define LSEQ   4096
#define DHD    64
#define NHASH  4
#define CDIM   512
#define NBH    32        // B*HEADS
#define MROWS  16384     // B*LSEQ
#define NCHUNK 256       // NHASH*LSEQ/64

// ---------------------------------------------------------------------------
// K1: qk/v projection GEMM.  X(16384x512) @ W(512x512) -> (bh, t, dh) layout.
// grid (128, 8, 2), block 256.  Tile 128x64, BK=32, thread tile 8x4.
// ---------------------------------------------------------------------------
__global__ __launch_bounds__(256) void gemm_in_kernel(
    const float* __restrict__ X, const float* __restrict__ Wqk,
    const float* __restrict__ Wv, float* __restrict__ qk, float* __restrict__ v)
{
  const float* W = blockIdx.z ? Wv : Wqk;
  float* out = blockIdx.z ? v : qk;
  const int m0 = blockIdx.x * 128;
  const int n0 = blockIdx.y * 64;
  __shared__ float As[32][132];   // [k][m] transposed
  __shared__ float Bs[32][68];    // [k][n]
  const int tid = threadIdx.x;
  const int r = tid >> 4, c = tid & 15;   // rows 8r..8r+7, cols 4c..4c+3
  float acc[8][4];
#pragma unroll
  for (int i = 0; i < 8; i++)
#pragma unroll
    for (int j = 0; j < 4; j++) acc[i][j] = 0.f;

  const int arow = tid >> 3;   // 0..31
  const int ac4  = tid & 7;    // k-chunk
  const int brow = tid >> 4;   // 0..15
  const int bc4  = tid & 15;

  for (int kb = 0; kb < CDIM; kb += 32) {
    // stage A (transposed)
#pragma unroll
    for (int rr = 0; rr < 4; rr++) {
      int m = arow + rr * 32;
      float4 av = *reinterpret_cast<const float4*>(&X[(size_t)(m0 + m) * CDIM + kb + ac4 * 4]);
      As[ac4 * 4 + 0][m] = av.x;
      As[ac4 * 4 + 1][m] = av.y;
      As[ac4 * 4 + 2][m] = av.z;
      As[ac4 * 4 + 3][m] = av.w;
    }
    // stage B
#pragma unroll
    for (int rr = 0; rr < 2; rr++) {
      int kk = brow + rr * 16;
      *reinterpret_cast<float4*>(&Bs[kk][bc4 * 4]) =
          *reinterpret_cast<const float4*>(&W[(size_t)(kb + kk) * CDIM + n0 + bc4 * 4]);
    }
    __syncthreads();
#pragma unroll
    for (int k = 0; k < 32; k++) {
      float4 a0 = *reinterpret_cast<const float4*>(&As[k][r * 8]);
      float4 a1 = *reinterpret_cast<const float4*>(&As[k][r * 8 + 4]);
      float4 b  = *reinterpret_cast<const float4*>(&Bs[k][c * 4]);
      float am[8] = {a0.x, a0.y, a0.z, a0.w, a1.x, a1.y, a1.z, a1.w};
      float bn[4] = {b.x, b.y, b.z, b.w};
#pragma unroll
      for (int i = 0; i < 8; i++)
#pragma unroll
        for (int j = 0; j < 4; j++) acc[i][j] += am[i] * bn[j];
    }
    __syncthreads();
  }
  // epilogue: out[((b*8+head)*4096 + t)*64 + d]
  const int head = n0 >> 6;
#pragma unroll
  for (int ii = 0; ii < 8; ii++) {
    int m = m0 + r * 8 + ii;
    int b = m >> 12, t = m & 4095;
    float4 ov = {acc[ii][0], acc[ii][1], acc[ii][2], acc[ii][3]};
    *reinterpret_cast<float4*>(&out[(((size_t)(b * 8 + head) * LSEQ + t) * DHD) + c * 4]) = ov;
  }
}

// ---------------------------------------------------------------------------
// K2: LSH hashing.  buckets[bh][h][t] = argmax over [rot, -rot] (first wins).
// grid (16, 32), block 256: one thread per t.
// ---------------------------------------------------------------------------
__global__ __launch_bounds__(256) void hash_kernel(
    const float* __restrict__ qk, const float* __restrict__ rot,
    int* __restrict__ buckets)
{
  __shared__ float rotT[128][68];   // [h*32+i][f]
  const int tid = threadIdx.x;
  for (int idx = tid; idx < 64 * 128; idx += 256) {
    int f = idx >> 7, hi = idx & 127;
    rotT[hi][f] = rot[idx];
  }
  __syncthreads();
  const int bh = blockIdx.y;
  const int t = blockIdx.x * 256 + tid;
  float4 row4[16];
  const float* src = &qk[((size_t)bh * LSEQ + t) * DHD];
#pragma unroll
  for (int i = 0; i < 16; i++) row4[i] = reinterpret_cast<const float4*>(src)[i];

  int* bout = &buckets[(size_t)bh * NHASH * LSEQ];
  for (int h = 0; h < NHASH; h++) {
    float rc[32];
    float best = -3.0e38f;
    int bidx = 0;
#pragma unroll 4
    for (int i = 0; i < 32; i++) {
      const float* rr = &rotT[h * 32 + i][0];
      float a = 0.f;
#pragma unroll
      for (int f4 = 0; f4 < 16; f4++) {
        float4 rv = reinterpret_cast<const float4*>(rr)[f4];
        a += row4[f4].x * rv.x + row4[f4].y * rv.y + row4[f4].z * rv.z + row4[f4].w * rv.w;
      }
      rc[i] = a;
      if (a > best) { best = a; bidx = i; }
    }
#pragma unroll
    for (int i = 0; i < 32; i++) {
      float nv = -rc[i];
      if (nv > best) { best = nv; bidx = 32 + i; }
    }
    bout[h * LSEQ + t] = bidx;
  }
}

// ---------------------------------------------------------------------------
// K3: stable counting sort per (bh, h).  grid (4, 32), block 256.
// st[bh][h*4096 + rank] = pos   (sorted by bucket then pos; keys are unique)
// ---------------------------------------------------------------------------
__global__ __launch_bounds__(256) void sort_kernel(
    const int* __restrict__ buckets, int* __restrict__ st)
{
  __shared__ int hist[64][64];   // [seg][bucket] -> later repurposed as segbase
  const int h = blockIdx.x, bh = blockIdx.y;
  const int tid = threadIdx.x;
  const int* bk = &buckets[((size_t)bh * NHASH + h) * LSEQ];

  for (int i = tid; i < 64 * 64; i += 256) (&hist[0][0])[i] = 0;
  __syncthreads();
  for (int t = tid; t < LSEQ; t += 256) {
    int b = bk[t];
    atomicAdd(&hist[t >> 6][b], 1);
  }
  __syncthreads();
  if (tid < 64) {
    int tot = 0;
    for (int s = 0; s < 64; s++) tot += hist[s][tid];
    int vsc = tot;
    for (int off = 1; off < 64; off <<= 1) {
      int nv = __shfl_up(vsc, off, 64);
      if (tid >= off) vsc += nv;
    }
    int run = h * LSEQ + (vsc - tot);   // exclusive prefix + hash base
    for (int s = 0; s < 64; s++) {
      int tmp = hist[s][tid];
      hist[s][tid] = run;
      run += tmp;
    }
  }
  __syncthreads();
  const int wave = tid >> 6, lane = tid & 63;
  for (int si = 0; si < 16; si++) {
    int seg = wave * 16 + si;
    int pos = seg * 64 + lane;
    int b = bk[pos];
    int rank = 0;
    for (int k = 0; k < 64; k++) {
      int bb = __shfl(b, k, 64);
      rank += (bb == b && k < lane) ? 1 : 0;
    }
    int dest = hist[seg][b] + rank;
    st[(size_t)bh * (NHASH * LSEQ) + dest] = pos;
  }
}

// ---------------------------------------------------------------------------
// K4: chunked attention.  grid (256, 32), block 256 (one 64-row chunk).
// Writes o (bh, h*4096+pos, dh) and lse (bh, h*4096+pos) UNSORTED directly.
// ---------------------------------------------------------------------------
__global__ __launch_bounds__(256) void attn_kernel(
    const float* __restrict__ qk, const float* __restrict__ v,
    const int* __restrict__ st, float* __restrict__ o, float* __restrict__ lse_out)
{
  __shared__ float qs[64 * 64];     // swizzled rows
  __shared__ float ks[128 * 64];    // normalized, swizzled
  __shared__ float vs[128 * 64];    // swizzled
  __shared__ float ss[64 * 132];    // scores / probs
  __shared__ int qpos[64];
  __shared__ int kpos[128];

  const int cchunk = blockIdx.x, bh = blockIdx.y;
  const int tid = threadIdx.x;
  const int prev = (cchunk + NCHUNK - 1) & (NCHUNK - 1);
  const int* stb = &st[(size_t)bh * (NHASH * LSEQ)];

  if (tid < 64) qpos[tid] = stb[cchunk * 64 + tid];
  else if (tid < 192) {
    int j = tid - 64;
    kpos[j] = (j < 64) ? stb[prev * 64 + j] : stb[cchunk * 64 + (j - 64)];
  }
  __syncthreads();

  // stage q (64 rows x 16 float4)
  {
    const float* base = &qk[(size_t)bh * LSEQ * DHD];
#pragma unroll
    for (int it = 0; it < 4; it++) {
      int idx = tid + it * 256;
      int row = idx >> 4, d4 = idx & 15;
      float4 val = *reinterpret_cast<const float4*>(&base[(size_t)qpos[row] * DHD + d4 * 4]);
      int slot = (d4 + (row >> 3)) & 15;
      *reinterpret_cast<float4*>(&qs[row * 64 + slot * 4]) = val;
    }
  }
  // stage k (normalized) and v: 2 threads per row, 8 chunks each
  {
    int row = tid >> 1, p = tid & 1;
    const float* kb2 = &qk[((size_t)bh * LSEQ + kpos[row]) * DHD];
    float4 tmp[8];
    float ssum = 0.f;
#pragma unroll
    for (int q8 = 0; q8 < 8; q8++) {
      tmp[q8] = *reinterpret_cast<const float4*>(&kb2[(p * 8 + q8) * 4]);
      ssum += tmp[q8].x * tmp[q8].x + tmp[q8].y * tmp[q8].y +
              tmp[q8].z * tmp[q8].z + tmp[q8].w * tmp[q8].w;
    }
    ssum += __shfl_xor(ssum, 1, 64);
    float scale = 1.0f / fmaxf(sqrtf(ssum), 1e-12f);
#pragma unroll
    for (int q8 = 0; q8 < 8; q8++) {
      int d4 = p * 8 + q8;
      int slot = (d4 + (row >> 3)) & 15;
      float4 tv = tmp[q8];
      tv.x *= scale; tv.y *= scale; tv.z *= scale; tv.w *= scale;
      *reinterpret_cast<float4*>(&ks[row * 64 + slot * 4]) = tv;
    }
    const float* vb2 = &v[((size_t)bh * LSEQ + kpos[row]) * DHD];
#pragma unroll
    for (int q8 = 0; q8 < 8; q8++) {
      int d4 = p * 8 + q8;
      int slot = (d4 + (row >> 3)) & 15;
      *reinterpret_cast<float4*>(&vs[row * 64 + slot * 4]) =
          *reinterpret_cast<const float4*>(&vb2[d4 * 4]);
    }
  }
  __syncthreads();

  // dots: S = Q K^T * 0.125, masked.  thread (r,c): rows 4r.., cols 8c..
  {
    const int r = tid >> 4, c = tid & 15;
    float acc[4][8];
#pragma unroll
    for (int i = 0; i < 4; i++)
#pragma unroll
      for (int j = 0; j < 8; j++) acc[i][j] = 0.f;
#pragma unroll 4
    for (int d4 = 0; d4 < 16; d4++) {
      int kslot = (d4 + c) & 15;
      float4 kv[8];
#pragma unroll
      for (int jj = 0; jj < 8; jj++)
        kv[jj] = *reinterpret_cast<const float4*>(&ks[(8 * c + jj) * 64 + kslot * 4]);
      int qsl = (d4 + (r >> 1)) & 15;
#pragma unroll
      for (int ii = 0; ii < 4; ii++) {
        float4 qv = *reinterpret_cast<const float4*>(&qs[(4 * r + ii) * 64 + qsl * 4]);
#pragma unroll
        for (int jj = 0; jj < 8; jj++)
          acc[ii][jj] += qv.x * kv[jj].x + qv.y * kv[jj].y + qv.z * kv[jj].z + qv.w * kv[jj].w;
      }
    }
#pragma unroll
    for (int ii = 0; ii < 4; ii++) {
      int qrow = 4 * r + ii;
      int qp = qpos[qrow];
#pragma unroll
      for (int jj = 0; jj < 8; jj++) {
        int col = 8 * c + jj;
        float val = acc[ii][jj] * 0.125f;
        if (qp == kpos[col]) val = -5e4f;
        ss[qrow * 132 + col] = val;
      }
    }
  }
  __syncthreads();

  // softmax + lse.  thread (row = tid>>2, p = tid&3), cols p + 4k
  {
    const int row = tid >> 2, p = tid & 3;
    float m = -3.0e38f;
    for (int k = 0; k < 32; k++) m = fmaxf(m, ss[row * 132 + p + 4 * k]);
    m = fmaxf(m, __shfl_xor(m, 1, 64));
    m = fmaxf(m, __shfl_xor(m, 2, 64));
    float s = 0.f;
    for (int k = 0; k < 32; k++) s += __expf(ss[row * 132 + p + 4 * k] - m);
    s += __shfl_xor(s, 1, 64);
    s += __shfl_xor(s, 2, 64);
    float inv = 1.0f / s;
    if (p == 0) {
      int h = cchunk >> 6;
      lse_out[(size_t)bh * (NHASH * LSEQ) + h * LSEQ + qpos[row]] = m + __logf(s);
    }
    for (int k = 0; k < 32; k++) {
      int idx = row * 132 + p + 4 * k;
      ss[idx] = __expf(ss[idx] - m) * inv;
    }
  }
  __syncthreads();

  // PV: O = P(64x128) @ V(128x64).  thread (r2,c2): rows 4r2.., cols 4c2..
  {
    const int r2 = tid >> 4, c2 = tid & 15;
    float oacc[4][4];
#pragma unroll
    for (int i = 0; i < 4; i++)
#pragma unroll
      for (int j = 0; j < 4; j++) oacc[i][j] = 0.f;
#pragma unroll 4
    for (int jb = 0; jb < 32; jb++) {
      float4 pv[4];
#pragma unroll
      for (int ii = 0; ii < 4; ii++)
        pv[ii] = *reinterpret_cast<const float4*>(&ss[(4 * r2 + ii) * 132 + 4 * jb]);
      int vslot = (c2 + (jb >> 1)) & 15;
      float4 vv[4];
#pragma unroll
      for (int jj = 0; jj < 4; jj++)
        vv[jj] = *reinterpret_cast<const float4*>(&vs[(4 * jb + jj) * 64 + vslot * 4]);
#pragma unroll
      for (int ii = 0; ii < 4; ii++) {
        float p0 = pv[ii].x, p1 = pv[ii].y, p2 = pv[ii].z, p3 = pv[ii].w;
        oacc[ii][0] += p0 * vv[0].x + p1 * vv[1].x + p2 * vv[2].x + p3 * vv[3].x;
        oacc[ii][1] += p0 * vv[0].y + p1 * vv[1].y + p2 * vv[2].y + p3 * vv[3].y;
        oacc[ii][2] += p0 * vv[0].z + p1 * vv[1].z + p2 * vv[2].z + p3 * vv[3].z;
        oacc[ii][3] += p0 * vv[0].w + p1 * vv[1].w + p2 * vv[2].w + p3 * vv[3].w;
      }
    }
    const int h = cchunk >> 6;
#pragma unroll
    for (int ii = 0; ii < 4; ii++) {
      int qrow = 4 * r2 + ii;
      float4 ov = {oacc[ii][0], oacc[ii][1], oacc[ii][2], oacc[ii][3]};
      *reinterpret_cast<float4*>(
          &o[((size_t)bh * (NHASH * LSEQ) + h * LSEQ + qpos[qrow]) * DHD + 4 * c2]) = ov;
    }
  }
}

// ---------------------------------------------------------------------------
// K5: combine hash rounds.  grid 32768, block 256 (4 rows x 64 lanes).
// comb[(b*4096+pos)*512 + head*64 + d]
// ---------------------------------------------------------------------------
__global__ __launch_bounds__(256) void combine_kernel(
    const float* __restrict__ o, const float* __restrict__ lse,
    float* __restrict__ comb)
{
  int gid = blockIdx.x * 4 + (threadIdx.x >> 6);
  int lane = threadIdx.x & 63;
  int bh = gid >> 12;
  int pos = gid & 4095;
  const float* lb = &lse[(size_t)bh * (NHASH * LSEQ) + pos];
  float l0 = lb[0], l1 = lb[LSEQ], l2 = lb[2 * LSEQ], l3 = lb[3 * LSEQ];
  float m = fmaxf(fmaxf(l0, l1), fmaxf(l2, l3));
  float w0 = __expf(l0 - m), w1 = __expf(l1 - m), w2 = __expf(l2 - m), w3 = __expf(l3 - m);
  float inv = 1.0f / (w0 + w1 + w2 + w3);
  const float* ob = &o[((size_t)bh * (NHASH * LSEQ) + pos) * DHD];
  float val = (w0 * ob[lane] + w1 * ob[(size_t)LSEQ * DHD + lane] +
               w2 * ob[(size_t)2 * LSEQ * DHD + lane] +
               w3 * ob[(size_t)3 * LSEQ * DHD + lane]) * inv;
  int b = bh >> 3, head = bh & 7;
  comb[((size_t)(b * LSEQ + pos)) * CDIM + head * DHD + lane] = val;
}

// ---------------------------------------------------------------------------
// K6: output GEMM + bias.  comb(16384x512) @ Wo(512x512) + bo -> d_out
// ---------------------------------------------------------------------------
__global__ __launch_bounds__(256) void gemm_out_kernel(
    const float* __restrict__ A, const float* __restrict__ W,
    const float* __restrict__ bias, float* __restrict__ out)
{
  const int m0 = blockIdx.x * 128;
  const int n0 = blockIdx.y * 64;
  __shared__ float As[32][132];
  __shared__ float Bs[32][68];
  const int tid = threadIdx.x;
  const int r = tid >> 4, c = tid & 15;
  float acc[8][4];
#pragma unroll
  for (int i = 0; i < 8; i++)
#pragma unroll
    for (int j = 0; j < 4; j++) acc[i][j] = 0.f;

  const int arow = tid >> 3;
  const int ac4  = tid & 7;
  const int brow = tid >> 4;
  const int bc4  = tid & 15;

  for (int kb = 0; kb < CDIM; kb += 32) {
#pragma unroll
    for (int rr = 0; rr < 4; rr++) {
      int m = arow + rr * 32;
      float4 av = *reinterpret_cast<const float4*>(&A[(size_t)(m0 + m) * CDIM + kb + ac4 * 4]);
      As[ac4 * 4 + 0][m] = av.x;
      As[ac4 * 4 + 1][m] = av.y;
      As[ac4 * 4 + 2][m] = av.z;
      As[ac4 * 4 + 3][m] = av.w;
    }
#pragma unroll
    for (int rr = 0; rr < 2; rr++) {
      int kk = brow + rr * 16;
      *reinterpret_cast<float4*>(&Bs[kk][bc4 * 4]) =
          *reinterpret_cast<const float4*>(&W[(size_t)(kb + kk) * CDIM + n0 + bc4 * 4]);
    }
    __syncthreads();
#pragma unroll
    for (int k = 0; k < 32; k++) {
      float4 a0 = *reinterpret_cast<const float4*>(&As[k][r * 8]);
      float4 a1 = *reinterpret_cast<const float4*>(&As[k][r * 8 + 4]);
      float4 b  = *reinterpret_cast<const float4*>(&Bs[k][c * 4]);
      float am[8] = {a0.x, a0.y, a0.z, a0.w, a1.x, a1.y, a1.z, a1.w};
      float bn[4] = {b.x, b.y, b.z, b.w};
#pragma unroll
      for (int i = 0; i < 8; i++)
#pragma unroll
        for (int j = 0; j < 4; j++) acc[i][j] += am[i] * bn[j];
    }
    __syncthreads();
  }
  float4 bv = *reinterpret_cast<const float4*>(&bias[n0 + c * 4]);
#pragma unroll
  for (int ii = 0; ii < 8; ii++) {
    int m = m0 + r * 8 + ii;
    float4 ov = {acc[ii][0] + bv.x, acc[ii][1] + bv.y, acc[ii][2] + bv.z, acc[ii][3] + bv.w};
    *reinterpret_cast<float4*>(&out[(size_t)m * CDIM + n0 + c * 4]) = ov;
  }
}

// ---------------------------------------------------------------------------
extern "C" void kernel_launch(void* const* d_in, const int* in_sizes, int n_in,
                              void* d_out, int out_size, void* d_ws, size_t ws_size,
                              hipStream_t stream) {
  (void)in_sizes; (void)n_in; (void)out_size;
  const float* X    = (const float*)d_in[0];   // queries (4,4096,512)
  const float* Wqk  = (const float*)d_in[6];
  const float* Wv   = (const float*)d_in[7];
  const float* Wo   = (const float*)d_in[8];
  const float* bo   = (const float*)d_in[9];
  const float* rot  = (const float*)d_in[10];  // (64, 4, 32)

  // workspace layout (floats); total ~198 MB
  float* ws = (float*)d_ws;
  float* qk      = ws;                         //  8,388,608 f
  float* vv      = ws + 8388608;               //  8,388,608 f
  float* obuf    = ws + 16777216;              // 33,554,432 f
  int*   buckets = (int*)(ws + 50331648);      //    524,288 i
  int*   st      = (int*)(ws + 50855936);      //    524,288 i
  float* lse     = ws + 51380224;              //    524,288 f
  float* comb    = qk;                         // alias: qk dead after attention
  (void)ws_size;

  hipLaunchKernelGGL(gemm_in_kernel, dim3(128, 8, 2), dim3(256), 0, stream,
                     X, Wqk, Wv, qk, vv);
  hipLaunchKernelGGL(hash_kernel, dim3(16, 32), dim3(256), 0, stream,
                     qk, rot, buckets);
  hipLaunchKernelGGL(sort_kernel, dim3(4, 32), dim3(256), 0, stream,
                     buckets, st);
  hipLaunchKernelGGL(attn_kernel, dim3(256, 32), dim3(256), 0, stream,
                     qk, vv, st, obuf, lse);
  hipLaunchKernelGGL(combine_kernel, dim3(32768), dim3(256), 0, stream,
                     obuf, lse, comb);
  hipLaunchKernelGGL(gemm_out_kernel, dim3(128, 8), dim3(256), 0, stream,
                     comb, Wo, bo, (float*)d_out);
}

// Round 2
// 852.158 us; speedup vs baseline: 1.1138x; 1.1138x over previous
//
#include <hip/hip_runtime.h>
#include <hip/hip_bf16.h>
#include <cstdint>
#include <cstddef>

// Problem constants (fixed by setup_inputs)
#define LSEQ   4096
#define DHD    64
#define NHASH  4
#define CDIM   512
#define NBH    32        // B*HEADS
#define MROWS  16384     // B*LSEQ
#define NCHUNK 256       // NHASH*LSEQ/64

// ---------------------------------------------------------------------------
// K1: qk/v projection GEMM.  X(16384x512) @ W(512x512) -> (bh, t, dh) layout.
// grid (128, 8, 2), block 256.  Tile 128x64, BK=32, thread tile 8x4.
// ---------------------------------------------------------------------------
__global__ __launch_bounds__(256) void gemm_in_kernel(
    const float* __restrict__ X, const float* __restrict__ Wqk,
    const float* __restrict__ Wv, float* __restrict__ qk, float* __restrict__ v)
{
  const float* W = blockIdx.z ? Wv : Wqk;
  float* out = blockIdx.z ? v : qk;
  const int m0 = blockIdx.x * 128;
  const int n0 = blockIdx.y * 64;
  __shared__ float As[32][132];   // [k][m] transposed
  __shared__ float Bs[32][68];    // [k][n]
  const int tid = threadIdx.x;
  const int r = tid >> 4, c = tid & 15;   // rows 8r..8r+7, cols 4c..4c+3
  float acc[8][4];
#pragma unroll
  for (int i = 0; i < 8; i++)
#pragma unroll
    for (int j = 0; j < 4; j++) acc[i][j] = 0.f;

  const int arow = tid >> 3;   // 0..31
  const int ac4  = tid & 7;    // k-chunk
  const int brow = tid >> 4;   // 0..15
  const int bc4  = tid & 15;

  for (int kb = 0; kb < CDIM; kb += 32) {
    // stage A (transposed)
#pragma unroll
    for (int rr = 0; rr < 4; rr++) {
      int m = arow + rr * 32;
      float4 av = *reinterpret_cast<const float4*>(&X[(size_t)(m0 + m) * CDIM + kb + ac4 * 4]);
      As[ac4 * 4 + 0][m] = av.x;
      As[ac4 * 4 + 1][m] = av.y;
      As[ac4 * 4 + 2][m] = av.z;
      As[ac4 * 4 + 3][m] = av.w;
    }
    // stage B
#pragma unroll
    for (int rr = 0; rr < 2; rr++) {
      int kk = brow + rr * 16;
      *reinterpret_cast<float4*>(&Bs[kk][bc4 * 4]) =
          *reinterpret_cast<const float4*>(&W[(size_t)(kb + kk) * CDIM + n0 + bc4 * 4]);
    }
    __syncthreads();
#pragma unroll
    for (int k = 0; k < 32; k++) {
      float4 a0 = *reinterpret_cast<const float4*>(&As[k][r * 8]);
      float4 a1 = *reinterpret_cast<const float4*>(&As[k][r * 8 + 4]);
      float4 b  = *reinterpret_cast<const float4*>(&Bs[k][c * 4]);
      float am[8] = {a0.x, a0.y, a0.z, a0.w, a1.x, a1.y, a1.z, a1.w};
      float bn[4] = {b.x, b.y, b.z, b.w};
#pragma unroll
      for (int i = 0; i < 8; i++)
#pragma unroll
        for (int j = 0; j < 4; j++) acc[i][j] += am[i] * bn[j];
    }
    __syncthreads();
  }
  // epilogue: out[((b*8+head)*4096 + t)*64 + d]
  const int head = n0 >> 6;
#pragma unroll
  for (int ii = 0; ii < 8; ii++) {
    int m = m0 + r * 8 + ii;
    int b = m >> 12, t = m & 4095;
    float4 ov = {acc[ii][0], acc[ii][1], acc[ii][2], acc[ii][3]};
    *reinterpret_cast<float4*>(&out[(((size_t)(b * 8 + head) * LSEQ + t) * DHD) + c * 4]) = ov;
  }
}

// ---------------------------------------------------------------------------
// K2: LSH hashing.  buckets[bh][h][t] = argmax over [rot, -rot] (first wins).
// grid (16, 32), block 256: one thread per t.
// ---------------------------------------------------------------------------
__global__ __launch_bounds__(256) void hash_kernel(
    const float* __restrict__ qk, const float* __restrict__ rot,
    int* __restrict__ buckets)
{
  __shared__ float rotT[128][68];   // [h*32+i][f]
  const int tid = threadIdx.x;
  for (int idx = tid; idx < 64 * 128; idx += 256) {
    int f = idx >> 7, hi = idx & 127;
    rotT[hi][f] = rot[idx];
  }
  __syncthreads();
  const int bh = blockIdx.y;
  const int t = blockIdx.x * 256 + tid;
  float4 row4[16];
  const float* src = &qk[((size_t)bh * LSEQ + t) * DHD];
#pragma unroll
  for (int i = 0; i < 16; i++) row4[i] = reinterpret_cast<const float4*>(src)[i];

  int* bout = &buckets[(size_t)bh * NHASH * LSEQ];
  for (int h = 0; h < NHASH; h++) {
    float rc[32];
    float best = -3.0e38f;
    int bidx = 0;
#pragma unroll 4
    for (int i = 0; i < 32; i++) {
      const float* rr = &rotT[h * 32 + i][0];
      float a = 0.f;
#pragma unroll
      for (int f4 = 0; f4 < 16; f4++) {
        float4 rv = reinterpret_cast<const float4*>(rr)[f4];
        a += row4[f4].x * rv.x + row4[f4].y * rv.y + row4[f4].z * rv.z + row4[f4].w * rv.w;
      }
      rc[i] = a;
      if (a > best) { best = a; bidx = i; }
    }
#pragma unroll
    for (int i = 0; i < 32; i++) {
      float nv = -rc[i];
      if (nv > best) { best = nv; bidx = 32 + i; }
    }
    bout[h * LSEQ + t] = bidx;
  }
}

// ---------------------------------------------------------------------------
// K3: stable counting sort per (bh, h).  grid (4, 32), block 256.
// st[bh][h*4096 + rank] = pos   (sorted by bucket then pos; keys are unique)
// ---------------------------------------------------------------------------
__global__ __launch_bounds__(256) void sort_kernel(
    const int* __restrict__ buckets, int* __restrict__ st)
{
  __shared__ int hist[64][64];   // [seg][bucket] -> later repurposed as segbase
  const int h = blockIdx.x, bh = blockIdx.y;
  const int tid = threadIdx.x;
  const int* bk = &buckets[((size_t)bh * NHASH + h) * LSEQ];

  for (int i = tid; i < 64 * 64; i += 256) (&hist[0][0])[i] = 0;
  __syncthreads();
  for (int t = tid; t < LSEQ; t += 256) {
    int b = bk[t];
    atomicAdd(&hist[t >> 6][b], 1);
  }
  __syncthreads();
  if (tid < 64) {
    int tot = 0;
    for (int s = 0; s < 64; s++) tot += hist[s][tid];
    int vsc = tot;
    for (int off = 1; off < 64; off <<= 1) {
      int nv = __shfl_up(vsc, off, 64);
      if (tid >= off) vsc += nv;
    }
    int run = h * LSEQ + (vsc - tot);   // exclusive prefix + hash base
    for (int s = 0; s < 64; s++) {
      int tmp = hist[s][tid];
      hist[s][tid] = run;
      run += tmp;
    }
  }
  __syncthreads();
  const int wave = tid >> 6, lane = tid & 63;
  for (int si = 0; si < 16; si++) {
    int seg = wave * 16 + si;
    int pos = seg * 64 + lane;
    int b = bk[pos];
    int rank = 0;
    for (int k = 0; k < 64; k++) {
      int bb = __shfl(b, k, 64);
      rank += (bb == b && k < lane) ? 1 : 0;
    }
    int dest = hist[seg][b] + rank;
    st[(size_t)bh * (NHASH * LSEQ) + dest] = pos;
  }
}

// ---------------------------------------------------------------------------
// K4: chunked attention, v2.  grid (256, 32), block 256 (one 64-row chunk).
//
// LDS: raw kv tile (128x64 f32, XOR-swizzled) + v tile (128x64) only.
//  - q rows are rows 64..127 of the kv tile (raw, unnormalized).
//  - k normalization folds into a per-column scale of the raw dots.
//  - softmax fully in registers (rows owned by 16 consecutive lanes).
//  - unnormalized P overwrites the kv tile (exactly 8192 words); O is
//    scaled by 1/rowsum at the store.
// 66.8 KB LDS -> 2 blocks/CU.  All LDS access patterns verified
// words-per-bank-minimal via XOR swizzles.
// ---------------------------------------------------------------------------
__global__ __launch_bounds__(256) void attn_kernel(
    const float* __restrict__ qk, const float* __restrict__ v,
    const int* __restrict__ st, float* __restrict__ o, float* __restrict__ lse_out)
{
  __shared__ float kv[128 * 64];   // raw qk rows (swizzled); later P[64][128]
  __shared__ float vs[128 * 64];   // v rows (swizzled)
  __shared__ float invn[128];
  __shared__ float rowsum[64];
  __shared__ int kpos[128];

  const int cchunk = blockIdx.x, bh = blockIdx.y;
  const int tid = threadIdx.x;
  const int prev = (cchunk + NCHUNK - 1) & (NCHUNK - 1);
  const int* stb = &st[(size_t)bh * (NHASH * LSEQ)];

  if (tid < 128) {
    kpos[tid] = (tid < 64) ? stb[prev * 64 + tid] : stb[cchunk * 64 + (tid - 64)];
  }
  __syncthreads();

  // ---- stage kv + v (swizzle: d4 ^= row>>3), compute invnorm per row ----
  {
    const int d4 = tid & 15;
    const int rbase = tid >> 4;
    const float* qb = &qk[(size_t)bh * LSEQ * DHD];
    const float* vb = &v[(size_t)bh * LSEQ * DHD];
#pragma unroll
    for (int it = 0; it < 8; it++) {
      int row = rbase + it * 16;
      int kp = kpos[row];
      int swz = ((d4 ^ (row >> 3)) & 15) * 4;
      float4 val = *reinterpret_cast<const float4*>(&qb[(size_t)kp * DHD + d4 * 4]);
      *reinterpret_cast<float4*>(&kv[row * 64 + swz]) = val;
      float ss = val.x * val.x + val.y * val.y + val.z * val.z + val.w * val.w;
      ss += __shfl_xor(ss, 1, 64);
      ss += __shfl_xor(ss, 2, 64);
      ss += __shfl_xor(ss, 4, 64);
      ss += __shfl_xor(ss, 8, 64);
      if (d4 == 0) invn[row] = 1.0f / fmaxf(sqrtf(ss), 1e-12f);
      float4 vv4 = *reinterpret_cast<const float4*>(&vb[(size_t)kp * DHD + d4 * 4]);
      *reinterpret_cast<float4*>(&vs[row * 64 + swz]) = vv4;
    }
  }
  __syncthreads();

  // ---- dots: raw scores, thread tile 4 rows x 8 cols ----
  const int r = tid >> 4, c = tid & 15;
  float acc[4][8];
#pragma unroll
  for (int i = 0; i < 4; i++)
#pragma unroll
    for (int j = 0; j < 8; j++) acc[i][j] = 0.f;

#pragma unroll 4
  for (int d4 = 0; d4 < 16; d4++) {
    const int ks_ = ((d4 ^ c) & 15) * 4;
    float4 kvv[8];
#pragma unroll
    for (int jj = 0; jj < 8; jj++)
      kvv[jj] = *reinterpret_cast<const float4*>(&kv[(8 * c + jj) * 64 + ks_]);
#pragma unroll
    for (int ii = 0; ii < 4; ii++) {
      int qsw = (((d4 ^ ((4 * r + ii) >> 3)) ^ 8) & 15) * 4;
      float4 qv = *reinterpret_cast<const float4*>(&kv[(64 + 4 * r + ii) * 64 + qsw]);
#pragma unroll
      for (int jj = 0; jj < 8; jj++)
        acc[ii][jj] += qv.x * kvv[jj].x + qv.y * kvv[jj].y +
                       qv.z * kvv[jj].z + qv.w * kvv[jj].w;
    }
  }
  __syncthreads();   // all kv-tile reads complete; safe to overwrite with P

  // ---- scale + mask + register softmax; write unnormalized P ----
  {
    float invc[8]; int kpc[8];
#pragma unroll
    for (int jj = 0; jj < 8; jj++) {
      invc[jj] = invn[8 * c + jj] * 0.125f;
      kpc[jj] = kpos[8 * c + jj];
    }
    const int h = cchunk >> 6;
#pragma unroll
    for (int ii = 0; ii < 4; ii++) {
      int qp = kpos[64 + 4 * r + ii];
      float mm = -3.0e38f;
#pragma unroll
      for (int jj = 0; jj < 8; jj++) {
        float s = acc[ii][jj] * invc[jj];
        if (qp == kpc[jj]) s = -5e4f;
        acc[ii][jj] = s;
        mm = fmaxf(mm, s);
      }
      mm = fmaxf(mm, __shfl_xor(mm, 1, 64));
      mm = fmaxf(mm, __shfl_xor(mm, 2, 64));
      mm = fmaxf(mm, __shfl_xor(mm, 4, 64));
      mm = fmaxf(mm, __shfl_xor(mm, 8, 64));
      float ll = 0.f;
#pragma unroll
      for (int jj = 0; jj < 8; jj++) {
        float p = __expf(acc[ii][jj] - mm);
        acc[ii][jj] = p;
        ll += p;
      }
      ll += __shfl_xor(ll, 1, 64);
      ll += __shfl_xor(ll, 2, 64);
      ll += __shfl_xor(ll, 4, 64);
      ll += __shfl_xor(ll, 8, 64);
      if (c == 0) {
        rowsum[4 * r + ii] = ll;
        lse_out[(size_t)bh * (NHASH * LSEQ) + h * LSEQ + qp] = mm + __logf(ll);
      }
      // write P row into kv space: word = row*128 + ((cb ^ (row>>2))&31)*4
      int row = 4 * r + ii;
#pragma unroll
      for (int b2 = 0; b2 < 2; b2++) {
        int scb = ((2 * c + b2) ^ r) & 31;
        float4 pv = {acc[ii][4 * b2 + 0], acc[ii][4 * b2 + 1],
                     acc[ii][4 * b2 + 2], acc[ii][4 * b2 + 3]};
        *reinterpret_cast<float4*>(&kv[row * 128 + scb * 4]) = pv;
      }
    }
  }
  __syncthreads();

  // ---- PV: O = P(64x128) @ V(128x64), thread tile 4 rows x 4 d-cols ----
  {
    float oacc[4][4];
#pragma unroll
    for (int i = 0; i < 4; i++)
#pragma unroll
      for (int j = 0; j < 4; j++) oacc[i][j] = 0.f;

#pragma unroll 4
    for (int jb = 0; jb < 32; jb++) {
      float4 pv[4];
#pragma unroll
      for (int ii = 0; ii < 4; ii++)
        pv[ii] = *reinterpret_cast<const float4*>(
            &kv[(4 * r + ii) * 128 + ((jb ^ r) & 31) * 4]);
      float4 vv[4];
#pragma unroll
      for (int jj = 0; jj < 4; jj++) {
        int j = 4 * jb + jj;
        vv[jj] = *reinterpret_cast<const float4*>(
            &vs[j * 64 + ((c ^ (j >> 3)) & 15) * 4]);
      }
#pragma unroll
      for (int ii = 0; ii < 4; ii++) {
        oacc[ii][0] += pv[ii].x * vv[0].x + pv[ii].y * vv[1].x + pv[ii].z * vv[2].x + pv[ii].w * vv[3].x;
        oacc[ii][1] += pv[ii].x * vv[0].y + pv[ii].y * vv[1].y + pv[ii].z * vv[2].y + pv[ii].w * vv[3].y;
        oacc[ii][2] += pv[ii].x * vv[0].z + pv[ii].y * vv[1].z + pv[ii].z * vv[2].z + pv[ii].w * vv[3].z;
        oacc[ii][3] += pv[ii].x * vv[0].w + pv[ii].y * vv[1].w + pv[ii].z * vv[2].w + pv[ii].w * vv[3].w;
      }
    }
    const int h = cchunk >> 6;
#pragma unroll
    for (int ii = 0; ii < 4; ii++) {
      int qrow = 4 * r + ii;
      float inv = 1.0f / rowsum[qrow];
      float4 ov = {oacc[ii][0] * inv, oacc[ii][1] * inv,
                   oacc[ii][2] * inv, oacc[ii][3] * inv};
      *reinterpret_cast<float4*>(
          &o[((size_t)bh * (NHASH * LSEQ) + h * LSEQ + kpos[64 + qrow]) * DHD + 4 * c]) = ov;
    }
  }
}

// ---------------------------------------------------------------------------
// K5: combine hash rounds.  grid 32768, block 256 (4 rows x 64 lanes).
// comb[(b*4096+pos)*512 + head*64 + d]
// ---------------------------------------------------------------------------
__global__ __launch_bounds__(256) void combine_kernel(
    const float* __restrict__ o, const float* __restrict__ lse,
    float* __restrict__ comb)
{
  int gid = blockIdx.x * 4 + (threadIdx.x >> 6);
  int lane = threadIdx.x & 63;
  int bh = gid >> 12;
  int pos = gid & 4095;
  const float* lb = &lse[(size_t)bh * (NHASH * LSEQ) + pos];
  float l0 = lb[0], l1 = lb[LSEQ], l2 = lb[2 * LSEQ], l3 = lb[3 * LSEQ];
  float m = fmaxf(fmaxf(l0, l1), fmaxf(l2, l3));
  float w0 = __expf(l0 - m), w1 = __expf(l1 - m), w2 = __expf(l2 - m), w3 = __expf(l3 - m);
  float inv = 1.0f / (w0 + w1 + w2 + w3);
  const float* ob = &o[((size_t)bh * (NHASH * LSEQ) + pos) * DHD];
  float val = (w0 * ob[lane] + w1 * ob[(size_t)LSEQ * DHD + lane] +
               w2 * ob[(size_t)2 * LSEQ * DHD + lane] +
               w3 * ob[(size_t)3 * LSEQ * DHD + lane]) * inv;
  int b = bh >> 3, head = bh & 7;
  comb[((size_t)(b * LSEQ + pos)) * CDIM + head * DHD + lane] = val;
}

// ---------------------------------------------------------------------------
// K6: output GEMM + bias.  comb(16384x512) @ Wo(512x512) + bo -> d_out
// ---------------------------------------------------------------------------
__global__ __launch_bounds__(256) void gemm_out_kernel(
    const float* __restrict__ A, const float* __restrict__ W,
    const float* __restrict__ bias, float* __restrict__ out)
{
  const int m0 = blockIdx.x * 128;
  const int n0 = blockIdx.y * 64;
  __shared__ float As[32][132];
  __shared__ float Bs[32][68];
  const int tid = threadIdx.x;
  const int r = tid >> 4, c = tid & 15;
  float acc[8][4];
#pragma unroll
  for (int i = 0; i < 8; i++)
#pragma unroll
    for (int j = 0; j < 4; j++) acc[i][j] = 0.f;

  const int arow = tid >> 3;
  const int ac4  = tid & 7;
  const int brow = tid >> 4;
  const int bc4  = tid & 15;

  for (int kb = 0; kb < CDIM; kb += 32) {
#pragma unroll
    for (int rr = 0; rr < 4; rr++) {
      int m = arow + rr * 32;
      float4 av = *reinterpret_cast<const float4*>(&A[(size_t)(m0 + m) * CDIM + kb + ac4 * 4]);
      As[ac4 * 4 + 0][m] = av.x;
      As[ac4 * 4 + 1][m] = av.y;
      As[ac4 * 4 + 2][m] = av.z;
      As[ac4 * 4 + 3][m] = av.w;
    }
#pragma unroll
    for (int rr = 0; rr < 2; rr++) {
      int kk = brow + rr * 16;
      *reinterpret_cast<float4*>(&Bs[kk][bc4 * 4]) =
          *reinterpret_cast<const float4*>(&W[(size_t)(kb + kk) * CDIM + n0 + bc4 * 4]);
    }
    __syncthreads();
#pragma unroll
    for (int k = 0; k < 32; k++) {
      float4 a0 = *reinterpret_cast<const float4*>(&As[k][r * 8]);
      float4 a1 = *reinterpret_cast<const float4*>(&As[k][r * 8 + 4]);
      float4 b  = *reinterpret_cast<const float4*>(&Bs[k][c * 4]);
      float am[8] = {a0.x, a0.y, a0.z, a0.w, a1.x, a1.y, a1.z, a1.w};
      float bn[4] = {b.x, b.y, b.z, b.w};
#pragma unroll
      for (int i = 0; i < 8; i++)
#pragma unroll
        for (int j = 0; j < 4; j++) acc[i][j] += am[i] * bn[j];
    }
    __syncthreads();
  }
  float4 bv = *reinterpret_cast<const float4*>(&bias[n0 + c * 4]);
#pragma unroll
  for (int ii = 0; ii < 8; ii++) {
    int m = m0 + r * 8 + ii;
    float4 ov = {acc[ii][0] + bv.x, acc[ii][1] + bv.y, acc[ii][2] + bv.z, acc[ii][3] + bv.w};
    *reinterpret_cast<float4*>(&out[(size_t)m * CDIM + n0 + c * 4]) = ov;
  }
}

// ---------------------------------------------------------------------------
extern "C" void kernel_launch(void* const* d_in, const int* in_sizes, int n_in,
                              void* d_out, int out_size, void* d_ws, size_t ws_size,
                              hipStream_t stream) {
  (void)in_sizes; (void)n_in; (void)out_size;
  const float* X    = (const float*)d_in[0];   // queries (4,4096,512)
  const float* Wqk  = (const float*)d_in[6];
  const float* Wv   = (const float*)d_in[7];
  const float* Wo   = (const float*)d_in[8];
  const float* bo   = (const float*)d_in[9];
  const float* rot  = (const float*)d_in[10];  // (64, 4, 32)

  // workspace layout (floats); total ~198 MB
  float* ws = (float*)d_ws;
  float* qk      = ws;                         //  8,388,608 f
  float* vv      = ws + 8388608;               //  8,388,608 f
  float* obuf    = ws + 16777216;              // 33,554,432 f
  int*   buckets = (int*)(ws + 50331648);      //    524,288 i
  int*   st      = (int*)(ws + 50855936);      //    524,288 i
  float* lse     = ws + 51380224;              //    524,288 f
  float* comb    = qk;                         // alias: qk dead after attention
  (void)ws_size;

  hipLaunchKernelGGL(gemm_in_kernel, dim3(128, 8, 2), dim3(256), 0, stream,
                     X, Wqk, Wv, qk, vv);
  hipLaunchKernelGGL(hash_kernel, dim3(16, 32), dim3(256), 0, stream,
                     qk, rot, buckets);
  hipLaunchKernelGGL(sort_kernel, dim3(4, 32), dim3(256), 0, stream,
                     buckets, st);
  hipLaunchKernelGGL(attn_kernel, dim3(256, 32), dim3(256), 0, stream,
                     qk, vv, st, obuf, lse);
  hipLaunchKernelGGL(combine_kernel, dim3(32768), dim3(256), 0, stream,
                     obuf, lse, comb);
  hipLaunchKernelGGL(gemm_out_kernel, dim3(128, 8), dim3(256), 0, stream,
                     comb, Wo, bo, (float*)d_out);
}

// Round 3
// 685.335 us; speedup vs baseline: 1.3849x; 1.2434x over previous
//
#include <hip/hip_runtime.h>
#include <hip/hip_bf16.h>
#include <cstdint>
#include <cstddef>

// Problem constants (fixed by setup_inputs)
#define LSEQ   4096
#define DHD    64
#define NHASH  4
#define CDIM   512
#define NBH    32        // B*HEADS
#define MROWS  16384     // B*LSEQ
#define NCHUNK 256       // NHASH*LSEQ/64

typedef __attribute__((ext_vector_type(8))) short short8;
typedef __attribute__((ext_vector_type(4))) float f32x4;

__device__ inline uint32_t f2bf(float f) {
  uint32_t u = __float_as_uint(f);
  return (u + 0x7FFFu + ((u >> 16) & 1u)) >> 16;
}
__device__ inline float bf2f(uint32_t h) { return __uint_as_float(h << 16); }
__device__ inline void split2(float f, uint32_t& hi, uint32_t& lo) {
  hi = f2bf(f);
  lo = f2bf(f - bf2f(hi));
}

// ---------------------------------------------------------------------------
// K1: qk/v projection GEMM.  X(16384x512) @ W(512x512) -> (bh, t, dh) layout.
// UNCHANGED from round 1/2 (bucket determinism: qk feeds the LSH argmax).
// ---------------------------------------------------------------------------
__global__ __launch_bounds__(256) void gemm_in_kernel(
    const float* __restrict__ X, const float* __restrict__ Wqk,
    const float* __restrict__ Wv, float* __restrict__ qk, float* __restrict__ v)
{
  const float* W = blockIdx.z ? Wv : Wqk;
  float* out = blockIdx.z ? v : qk;
  const int m0 = blockIdx.x * 128;
  const int n0 = blockIdx.y * 64;
  __shared__ float As[32][132];   // [k][m] transposed
  __shared__ float Bs[32][68];    // [k][n]
  const int tid = threadIdx.x;
  const int r = tid >> 4, c = tid & 15;   // rows 8r..8r+7, cols 4c..4c+3
  float acc[8][4];
#pragma unroll
  for (int i = 0; i < 8; i++)
#pragma unroll
    for (int j = 0; j < 4; j++) acc[i][j] = 0.f;

  const int arow = tid >> 3;   // 0..31
  const int ac4  = tid & 7;    // k-chunk
  const int brow = tid >> 4;   // 0..15
  const int bc4  = tid & 15;

  for (int kb = 0; kb < CDIM; kb += 32) {
    // stage A (transposed)
#pragma unroll
    for (int rr = 0; rr < 4; rr++) {
      int m = arow + rr * 32;
      float4 av = *reinterpret_cast<const float4*>(&X[(size_t)(m0 + m) * CDIM + kb + ac4 * 4]);
      As[ac4 * 4 + 0][m] = av.x;
      As[ac4 * 4 + 1][m] = av.y;
      As[ac4 * 4 + 2][m] = av.z;
      As[ac4 * 4 + 3][m] = av.w;
    }
    // stage B
#pragma unroll
    for (int rr = 0; rr < 2; rr++) {
      int kk = brow + rr * 16;
      *reinterpret_cast<float4*>(&Bs[kk][bc4 * 4]) =
          *reinterpret_cast<const float4*>(&W[(size_t)(kb + kk) * CDIM + n0 + bc4 * 4]);
    }
    __syncthreads();
#pragma unroll
    for (int k = 0; k < 32; k++) {
      float4 a0 = *reinterpret_cast<const float4*>(&As[k][r * 8]);
      float4 a1 = *reinterpret_cast<const float4*>(&As[k][r * 8 + 4]);
      float4 b  = *reinterpret_cast<const float4*>(&Bs[k][c * 4]);
      float am[8] = {a0.x, a0.y, a0.z, a0.w, a1.x, a1.y, a1.z, a1.w};
      float bn[4] = {b.x, b.y, b.z, b.w};
#pragma unroll
      for (int i = 0; i < 8; i++)
#pragma unroll
        for (int j = 0; j < 4; j++) acc[i][j] += am[i] * bn[j];
    }
    __syncthreads();
  }
  // epilogue: out[((b*8+head)*4096 + t)*64 + d]
  const int head = n0 >> 6;
#pragma unroll
  for (int ii = 0; ii < 8; ii++) {
    int m = m0 + r * 8 + ii;
    int b = m >> 12, t = m & 4095;
    float4 ov = {acc[ii][0], acc[ii][1], acc[ii][2], acc[ii][3]};
    *reinterpret_cast<float4*>(&out[(((size_t)(b * 8 + head) * LSEQ + t) * DHD) + c * 4]) = ov;
  }
}

// ---------------------------------------------------------------------------
// K2: LSH hashing.  UNCHANGED (bucket determinism).
// ---------------------------------------------------------------------------
__global__ __launch_bounds__(256) void hash_kernel(
    const float* __restrict__ qk, const float* __restrict__ rot,
    int* __restrict__ buckets)
{
  __shared__ float rotT[128][68];   // [h*32+i][f]
  const int tid = threadIdx.x;
  for (int idx = tid; idx < 64 * 128; idx += 256) {
    int f = idx >> 7, hi = idx & 127;
    rotT[hi][f] = rot[idx];
  }
  __syncthreads();
  const int bh = blockIdx.y;
  const int t = blockIdx.x * 256 + tid;
  float4 row4[16];
  const float* src = &qk[((size_t)bh * LSEQ + t) * DHD];
#pragma unroll
  for (int i = 0; i < 16; i++) row4[i] = reinterpret_cast<const float4*>(src)[i];

  int* bout = &buckets[(size_t)bh * NHASH * LSEQ];
  for (int h = 0; h < NHASH; h++) {
    float rc[32];
    float best = -3.0e38f;
    int bidx = 0;
#pragma unroll 4
    for (int i = 0; i < 32; i++) {
      const float* rr = &rotT[h * 32 + i][0];
      float a = 0.f;
#pragma unroll
      for (int f4 = 0; f4 < 16; f4++) {
        float4 rv = reinterpret_cast<const float4*>(rr)[f4];
        a += row4[f4].x * rv.x + row4[f4].y * rv.y + row4[f4].z * rv.z + row4[f4].w * rv.w;
      }
      rc[i] = a;
      if (a > best) { best = a; bidx = i; }
    }
#pragma unroll
    for (int i = 0; i < 32; i++) {
      float nv = -rc[i];
      if (nv > best) { best = nv; bidx = 32 + i; }
    }
    bout[h * LSEQ + t] = bidx;
  }
}

// ---------------------------------------------------------------------------
// K3: stable counting sort per (bh, h).  UNCHANGED.
// ---------------------------------------------------------------------------
__global__ __launch_bounds__(256) void sort_kernel(
    const int* __restrict__ buckets, int* __restrict__ st)
{
  __shared__ int hist[64][64];   // [seg][bucket] -> later repurposed as segbase
  const int h = blockIdx.x, bh = blockIdx.y;
  const int tid = threadIdx.x;
  const int* bk = &buckets[((size_t)bh * NHASH + h) * LSEQ];

  for (int i = tid; i < 64 * 64; i += 256) (&hist[0][0])[i] = 0;
  __syncthreads();
  for (int t = tid; t < LSEQ; t += 256) {
    int b = bk[t];
    atomicAdd(&hist[t >> 6][b], 1);
  }
  __syncthreads();
  if (tid < 64) {
    int tot = 0;
    for (int s = 0; s < 64; s++) tot += hist[s][tid];
    int vsc = tot;
    for (int off = 1; off < 64; off <<= 1) {
      int nv = __shfl_up(vsc, off, 64);
      if (tid >= off) vsc += nv;
    }
    int run = h * LSEQ + (vsc - tot);   // exclusive prefix + hash base
    for (int s = 0; s < 64; s++) {
      int tmp = hist[s][tid];
      hist[s][tid] = run;
      run += tmp;
    }
  }
  __syncthreads();
  const int wave = tid >> 6, lane = tid & 63;
  for (int si = 0; si < 16; si++) {
    int seg = wave * 16 + si;
    int pos = seg * 64 + lane;
    int b = bk[pos];
    int rank = 0;
    for (int k = 0; k < 64; k++) {
      int bb = __shfl(b, k, 64);
      rank += (bb == b && k < lane) ? 1 : 0;
    }
    int dest = hist[seg][b] + rank;
    st[(size_t)bh * (NHASH * LSEQ) + dest] = pos;
  }
}

// ---------------------------------------------------------------------------
// K4: chunked attention, v3 — bf16x3 split MFMA (16x16x32).
// grid (256, 32), block 256 (4 waves; wave w owns q-rows 16w..16w+15).
//
//  K planes  Khi/Klo [128][72] bf16 (rows 0..63 = prev chunk, 64..127 = cur;
//            q rows ARE rows 64..127).  Padded stride 144B -> conflict-free
//            b128 fragment reads.
//  V planes  Vthi/Vtlo [64][136] bf16, stored TRANSPOSED (d-major) via a
//            register 4x4 transpose at staging, so PV B-fragments are
//            contiguous 16B reads.
//  P32       [64][132] u32 (hi|lo packed), aliases the dead K planes.
//  Softmax   fully in registers on the MFMA D-layout.
//  mfma(a,b): D[arow][brow], arow=(lane>>4)*4+reg, brow=lane&15; both
//  fragments: lane holds operand-row (lane&15), k-chunk (lane>>4)*8.
// ---------------------------------------------------------------------------
__global__ __launch_bounds__(256) void attn_kernel(
    const float* __restrict__ qk, const float* __restrict__ v,
    const int* __restrict__ st, float* __restrict__ o, float* __restrict__ lse_out)
{
  __shared__ __align__(16) uint8_t smem[72704];
  uint16_t* Khi  = (uint16_t*)smem;                  // [128][72]
  uint16_t* Klo  = Khi + 128 * 72;                   // +18432 B
  uint16_t* Vthi = (uint16_t*)(smem + 36864);        // [64][136]
  uint16_t* Vtlo = Vthi + 64 * 136;                  // +17408 B
  float*    invn = (float*)(smem + 71680);           // 128 f
  int*      kpos = (int*)(smem + 72192);             // 128 i
  uint32_t* P32  = (uint32_t*)smem;                  // [64][132], alias K planes

  const int cchunk = blockIdx.x, bh = blockIdx.y;
  const int tid = threadIdx.x;
  const int prev = (cchunk + NCHUNK - 1) & (NCHUNK - 1);
  const int* stb = &st[(size_t)bh * (NHASH * LSEQ)];
  const int h = cchunk >> 6;

  if (tid < 128) {
    kpos[tid] = (tid < 64) ? stb[prev * 64 + tid] : stb[cchunk * 64 + (tid - 64)];
  }
  __syncthreads();

  // ---- stage K (hi/lo planes) + invn ----
  {
    const int d4 = tid & 15, rbase = tid >> 4;
    const float* qb = qk + (size_t)bh * LSEQ * DHD;
#pragma unroll
    for (int it = 0; it < 8; it++) {
      int row = rbase + it * 16;
      float4 val = *reinterpret_cast<const float4*>(&qb[(size_t)kpos[row] * DHD + d4 * 4]);
      float ss = val.x * val.x + val.y * val.y + val.z * val.z + val.w * val.w;
      ss += __shfl_xor(ss, 1, 64);
      ss += __shfl_xor(ss, 2, 64);
      ss += __shfl_xor(ss, 4, 64);
      ss += __shfl_xor(ss, 8, 64);
      if (d4 == 0) invn[row] = 1.0f / fmaxf(sqrtf(ss), 1e-12f);
      uint32_t h0, l0, h1, l1, h2, l2, h3, l3;
      split2(val.x, h0, l0); split2(val.y, h1, l1);
      split2(val.z, h2, l2); split2(val.w, h3, l3);
      uint2 hw = {(h1 << 16) | h0, (h3 << 16) | h2};
      uint2 lw = {(l1 << 16) | l0, (l3 << 16) | l2};
      *reinterpret_cast<uint2*>(Khi + row * 72 + d4 * 4) = hw;
      *reinterpret_cast<uint2*>(Klo + row * 72 + d4 * 4) = lw;
    }
  }
  // ---- stage V transposed (register 4x4 transpose) ----
  {
    const int d4 = tid & 15, jg0 = tid >> 4;
    const float* vb = v + (size_t)bh * LSEQ * DHD;
#pragma unroll
    for (int half = 0; half < 2; half++) {
      int jg = jg0 + half * 16;   // 0..31, covers j = 4*jg..4*jg+3
      float4 vr[4];
#pragma unroll
      for (int s = 0; s < 4; s++)
        vr[s] = *reinterpret_cast<const float4*>(&vb[(size_t)kpos[jg * 4 + s] * DHD + d4 * 4]);
#pragma unroll
      for (int i = 0; i < 4; i++) {
        int d = d4 * 4 + i;
        uint32_t e0h, e0l, e1h, e1l, e2h, e2l, e3h, e3l;
        split2((&vr[0].x)[i], e0h, e0l);
        split2((&vr[1].x)[i], e1h, e1l);
        split2((&vr[2].x)[i], e2h, e2l);
        split2((&vr[3].x)[i], e3h, e3l);
        uint2 hw = {(e1h << 16) | e0h, (e3h << 16) | e2h};
        uint2 lw = {(e1l << 16) | e0l, (e3l << 16) | e2l};
        *reinterpret_cast<uint2*>(Vthi + d * 136 + jg * 4) = hw;
        *reinterpret_cast<uint2*>(Vtlo + d * 136 + jg * 4) = lw;
      }
    }
  }
  __syncthreads();

  const int lane = tid & 63, w = tid >> 6;
  const int l16 = lane & 15, lg = lane >> 4;

  // ---- QK^T: S = Q.K^T (bf16x3), wave w -> q-rows 16w..16w+15 ----
  f32x4 acc[8];
#pragma unroll
  for (int nt = 0; nt < 8; nt++) acc[nt] = {0.f, 0.f, 0.f, 0.f};

#pragma unroll
  for (int ks = 0; ks < 2; ks++) {
    int aoff = (64 + w * 16 + l16) * 72 + ks * 32 + lg * 8;
    short8 a_hi = *reinterpret_cast<const short8*>(Khi + aoff);
    short8 a_lo = *reinterpret_cast<const short8*>(Klo + aoff);
#pragma unroll
    for (int nt = 0; nt < 8; nt++) {
      int boff = (nt * 16 + l16) * 72 + ks * 32 + lg * 8;
      short8 b_hi = *reinterpret_cast<const short8*>(Khi + boff);
      short8 b_lo = *reinterpret_cast<const short8*>(Klo + boff);
      acc[nt] = __builtin_amdgcn_mfma_f32_16x16x32_bf16(a_hi, b_hi, acc[nt], 0, 0, 0);
      acc[nt] = __builtin_amdgcn_mfma_f32_16x16x32_bf16(a_lo, b_hi, acc[nt], 0, 0, 0);
      acc[nt] = __builtin_amdgcn_mfma_f32_16x16x32_bf16(a_hi, b_lo, acc[nt], 0, 0, 0);
    }
  }

  // ---- register softmax on the D-layout ----
  float invc[8]; int kpc[8];
#pragma unroll
  for (int nt = 0; nt < 8; nt++) {
    invc[nt] = invn[nt * 16 + l16] * 0.125f;
    kpc[nt] = kpos[nt * 16 + l16];
  }
  float pll[4];
#pragma unroll
  for (int r = 0; r < 4; r++) {
    int q = w * 16 + lg * 4 + r;
    int qp = kpos[64 + q];
    float mm = -3.0e38f;
#pragma unroll
    for (int nt = 0; nt < 8; nt++) {
      float s = acc[nt][r] * invc[nt];
      if (qp == kpc[nt]) s = -5e4f;
      acc[nt][r] = s;
      mm = fmaxf(mm, s);
    }
    mm = fmaxf(mm, __shfl_xor(mm, 1, 64));
    mm = fmaxf(mm, __shfl_xor(mm, 2, 64));
    mm = fmaxf(mm, __shfl_xor(mm, 4, 64));
    mm = fmaxf(mm, __shfl_xor(mm, 8, 64));
    float ll = 0.f;
#pragma unroll
    for (int nt = 0; nt < 8; nt++) {
      float p = __expf(acc[nt][r] - mm);
      acc[nt][r] = p;
      ll += p;
    }
    ll += __shfl_xor(ll, 1, 64);
    ll += __shfl_xor(ll, 2, 64);
    ll += __shfl_xor(ll, 4, 64);
    ll += __shfl_xor(ll, 8, 64);
    if (l16 == 0)
      lse_out[(size_t)bh * (NHASH * LSEQ) + h * LSEQ + qp] = mm + __logf(ll);
    pll[r] = 1.0f / ll;
  }
  __syncthreads();   // all K-plane reads done across waves; safe to alias P32

  // ---- write P (packed hi|lo u32) ----
#pragma unroll
  for (int r = 0; r < 4; r++) {
    int q = w * 16 + lg * 4 + r;
#pragma unroll
    for (int nt = 0; nt < 8; nt++) {
      uint32_t phi, plo;
      split2(acc[nt][r], phi, plo);
      P32[q * 132 + nt * 16 + l16] = (plo << 16) | phi;
    }
  }
  // no barrier needed: wave reads back only its own 16 P rows

  // ---- PV: O = P.V (bf16x3) ----
  f32x4 oacc[4];
#pragma unroll
  for (int nt = 0; nt < 4; nt++) oacc[nt] = {0.f, 0.f, 0.f, 0.f};

#pragma unroll
  for (int ks = 0; ks < 4; ks++) {
    const uint32_t* pr = P32 + (w * 16 + l16) * 132 + ks * 32 + lg * 8;
    uint4 ua = *reinterpret_cast<const uint4*>(pr);
    uint4 ub = *reinterpret_cast<const uint4*>(pr + 4);
    uint32_t u[8] = {ua.x, ua.y, ua.z, ua.w, ub.x, ub.y, ub.z, ub.w};
    union { uint32_t w4[4]; short8 s8; } ph, pl;
#pragma unroll
    for (int k2 = 0; k2 < 4; k2++) {
      ph.w4[k2] = (u[2 * k2] & 0xffffu) | (u[2 * k2 + 1] << 16);
      pl.w4[k2] = (u[2 * k2] >> 16) | (u[2 * k2 + 1] & 0xffff0000u);
    }
#pragma unroll
    for (int nt = 0; nt < 4; nt++) {
      int voff = (nt * 16 + l16) * 136 + ks * 32 + lg * 8;
      short8 v_hi = *reinterpret_cast<const short8*>(Vthi + voff);
      short8 v_lo = *reinterpret_cast<const short8*>(Vtlo + voff);
      oacc[nt] = __builtin_amdgcn_mfma_f32_16x16x32_bf16(ph.s8, v_hi, oacc[nt], 0, 0, 0);
      oacc[nt] = __builtin_amdgcn_mfma_f32_16x16x32_bf16(pl.s8, v_hi, oacc[nt], 0, 0, 0);
      oacc[nt] = __builtin_amdgcn_mfma_f32_16x16x32_bf16(ph.s8, v_lo, oacc[nt], 0, 0, 0);
    }
  }

  // ---- normalize + write O (unsorted; per-element, 64B-coalesced) ----
  {
    float* ob = o + ((size_t)bh * (NHASH * LSEQ) + (size_t)h * LSEQ) * DHD;
#pragma unroll
    for (int r = 0; r < 4; r++) {
      int q = w * 16 + lg * 4 + r;
      int qp = kpos[64 + q];
      float s = pll[r];
#pragma unroll
      for (int nt = 0; nt < 4; nt++)
        ob[(size_t)qp * DHD + nt * 16 + l16] = oacc[nt][r] * s;
    }
  }
}

// ---------------------------------------------------------------------------
// K5: combine hash rounds.  UNCHANGED.
// ---------------------------------------------------------------------------
__global__ __launch_bounds__(256) void combine_kernel(
    const float* __restrict__ o, const float* __restrict__ lse,
    float* __restrict__ comb)
{
  int gid = blockIdx.x * 4 + (threadIdx.x >> 6);
  int lane = threadIdx.x & 63;
  int bh = gid >> 12;
  int pos = gid & 4095;
  const float* lb = &lse[(size_t)bh * (NHASH * LSEQ) + pos];
  float l0 = lb[0], l1 = lb[LSEQ], l2 = lb[2 * LSEQ], l3 = lb[3 * LSEQ];
  float m = fmaxf(fmaxf(l0, l1), fmaxf(l2, l3));
  float w0 = __expf(l0 - m), w1 = __expf(l1 - m), w2 = __expf(l2 - m), w3 = __expf(l3 - m);
  float inv = 1.0f / (w0 + w1 + w2 + w3);
  const float* ob = &o[((size_t)bh * (NHASH * LSEQ) + pos) * DHD];
  float val = (w0 * ob[lane] + w1 * ob[(size_t)LSEQ * DHD + lane] +
               w2 * ob[(size_t)2 * LSEQ * DHD + lane] +
               w3 * ob[(size_t)3 * LSEQ * DHD + lane]) * inv;
  int b = bh >> 3, head = bh & 7;
  comb[((size_t)(b * LSEQ + pos)) * CDIM + head * DHD + lane] = val;
}

// ---------------------------------------------------------------------------
// K6: output GEMM + bias.  UNCHANGED.
// ---------------------------------------------------------------------------
__global__ __launch_bounds__(256) void gemm_out_kernel(
    const float* __restrict__ A, const float* __restrict__ W,
    const float* __restrict__ bias, float* __restrict__ out)
{
  const int m0 = blockIdx.x * 128;
  const int n0 = blockIdx.y * 64;
  __shared__ float As[32][132];
  __shared__ float Bs[32][68];
  const int tid = threadIdx.x;
  const int r = tid >> 4, c = tid & 15;
  float acc[8][4];
#pragma unroll
  for (int i = 0; i < 8; i++)
#pragma unroll
    for (int j = 0; j < 4; j++) acc[i][j] = 0.f;

  const int arow = tid >> 3;
  const int ac4  = tid & 7;
  const int brow = tid >> 4;
  const int bc4  = tid & 15;

  for (int kb = 0; kb < CDIM; kb += 32) {
#pragma unroll
    for (int rr = 0; rr < 4; rr++) {
      int m = arow + rr * 32;
      float4 av = *reinterpret_cast<const float4*>(&A[(size_t)(m0 + m) * CDIM + kb + ac4 * 4]);
      As[ac4 * 4 + 0][m] = av.x;
      As[ac4 * 4 + 1][m] = av.y;
      As[ac4 * 4 + 2][m] = av.z;
      As[ac4 * 4 + 3][m] = av.w;
    }
#pragma unroll
    for (int rr = 0; rr < 2; rr++) {
      int kk = brow + rr * 16;
      *reinterpret_cast<float4*>(&Bs[kk][bc4 * 4]) =
          *reinterpret_cast<const float4*>(&W[(size_t)(kb + kk) * CDIM + n0 + bc4 * 4]);
    }
    __syncthreads();
#pragma unroll
    for (int k = 0; k < 32; k++) {
      float4 a0 = *reinterpret_cast<const float4*>(&As[k][r * 8]);
      float4 a1 = *reinterpret_cast<const float4*>(&As[k][r * 8 + 4]);
      float4 b  = *reinterpret_cast<const float4*>(&Bs[k][c * 4]);
      float am[8] = {a0.x, a0.y, a0.z, a0.w, a1.x, a1.y, a1.z, a1.w};
      float bn[4] = {b.x, b.y, b.z, b.w};
#pragma unroll
      for (int i = 0; i < 8; i++)
#pragma unroll
        for (int j = 0; j < 4; j++) acc[i][j] += am[i] * bn[j];
    }
    __syncthreads();
  }
  float4 bv = *reinterpret_cast<const float4*>(&bias[n0 + c * 4]);
#pragma unroll
  for (int ii = 0; ii < 8; ii++) {
    int m = m0 + r * 8 + ii;
    float4 ov = {acc[ii][0] + bv.x, acc[ii][1] + bv.y, acc[ii][2] + bv.z, acc[ii][3] + bv.w};
    *reinterpret_cast<float4*>(&out[(size_t)m * CDIM + n0 + c * 4]) = ov;
  }
}

// ---------------------------------------------------------------------------
extern "C" void kernel_launch(void* const* d_in, const int* in_sizes, int n_in,
                              void* d_out, int out_size, void* d_ws, size_t ws_size,
                              hipStream_t stream) {
  (void)in_sizes; (void)n_in; (void)out_size;
  const float* X    = (const float*)d_in[0];   // queries (4,4096,512)
  const float* Wqk  = (const float*)d_in[6];
  const float* Wv   = (const float*)d_in[7];
  const float* Wo   = (const float*)d_in[8];
  const float* bo   = (const float*)d_in[9];
  const float* rot  = (const float*)d_in[10];  // (64, 4, 32)

  // workspace layout (floats); total ~198 MB
  float* ws = (float*)d_ws;
  float* qk      = ws;                         //  8,388,608 f
  float* vv      = ws + 8388608;               //  8,388,608 f
  float* obuf    = ws + 16777216;              // 33,554,432 f
  int*   buckets = (int*)(ws + 50331648);      //    524,288 i
  int*   st      = (int*)(ws + 50855936);      //    524,288 i
  float* lse     = ws + 51380224;              //    524,288 f
  float* comb    = qk;                         // alias: qk dead after attention
  (void)ws_size;

  hipLaunchKernelGGL(gemm_in_kernel, dim3(128, 8, 2), dim3(256), 0, stream,
                     X, Wqk, Wv, qk, vv);
  hipLaunchKernelGGL(hash_kernel, dim3(16, 32), dim3(256), 0, stream,
                     qk, rot, buckets);
  hipLaunchKernelGGL(sort_kernel, dim3(4, 32), dim3(256), 0, stream,
                     buckets, st);
  hipLaunchKernelGGL(attn_kernel, dim3(256, 32), dim3(256), 0, stream,
                     qk, vv, st, obuf, lse);
  hipLaunchKernelGGL(combine_kernel, dim3(32768), dim3(256), 0, stream,
                     obuf, lse, comb);
  hipLaunchKernelGGL(gemm_out_kernel, dim3(128, 8), dim3(256), 0, stream,
                     comb, Wo, bo, (float*)d_out);
}

// Round 4
// 514.460 us; speedup vs baseline: 1.8449x; 1.3321x over previous
//
#include <hip/hip_runtime.h>
#include <hip/hip_bf16.h>
#include <cstdint>
#include <cstddef>

// Problem constants (fixed by setup_inputs)
#define LSEQ   4096
#define DHD    64
#define NHASH  4
#define CDIM   512
#define NBH    32        // B*HEADS
#define MROWS  16384     // B*LSEQ
#define NCHUNK 256       // NHASH*LSEQ/64

typedef __attribute__((ext_vector_type(8))) short short8;
typedef __attribute__((ext_vector_type(4))) float f32x4;

__device__ inline uint32_t f2bf(float f) {
  uint32_t u = __float_as_uint(f);
  return (u + 0x7FFFu + ((u >> 16) & 1u)) >> 16;
}
__device__ inline float bf2f(uint32_t h) { return __uint_as_float(h << 16); }
__device__ inline void split2(float f, uint32_t& hi, uint32_t& lo) {
  hi = f2bf(f);
  lo = f2bf(f - bf2f(hi));
}
__device__ inline short8 ldsK(const uint16_t* p) {   // two b64 reads -> short8
  union { uint2 u[2]; short8 s; } t;
  t.u[0] = *reinterpret_cast<const uint2*>(p);
  t.u[1] = *reinterpret_cast<const uint2*>(p + 4);
  return t.s;
}

// ---------------------------------------------------------------------------
// K1: qk/v projection GEMM.  CORE LOOP UNCHANGED (bitwise-identical qk ->
// identical buckets).  Epilogue additionally emits bf16 hi/lo planes of qk,
// bf16 hi plane of v, and invn = 1/||k|| per row.
// ---------------------------------------------------------------------------
__global__ __launch_bounds__(256) void gemm_in_kernel(
    const float* __restrict__ X, const float* __restrict__ Wqk,
    const float* __restrict__ Wv, float* __restrict__ qk,
    uint16_t* __restrict__ qkhi, uint16_t* __restrict__ qklo,
    uint16_t* __restrict__ vhi, float* __restrict__ invn_g)
{
  const float* W = blockIdx.z ? Wv : Wqk;
  const int m0 = blockIdx.x * 128;
  const int n0 = blockIdx.y * 64;
  __shared__ float As[32][132];   // [k][m] transposed
  __shared__ float Bs[32][68];    // [k][n]
  const int tid = threadIdx.x;
  const int r = tid >> 4, c = tid & 15;   // rows 8r..8r+7, cols 4c..4c+3
  float acc[8][4];
#pragma unroll
  for (int i = 0; i < 8; i++)
#pragma unroll
    for (int j = 0; j < 4; j++) acc[i][j] = 0.f;

  const int arow = tid >> 3;   // 0..31
  const int ac4  = tid & 7;    // k-chunk
  const int brow = tid >> 4;   // 0..15
  const int bc4  = tid & 15;

  for (int kb = 0; kb < CDIM; kb += 32) {
#pragma unroll
    for (int rr = 0; rr < 4; rr++) {
      int m = arow + rr * 32;
      float4 av = *reinterpret_cast<const float4*>(&X[(size_t)(m0 + m) * CDIM + kb + ac4 * 4]);
      As[ac4 * 4 + 0][m] = av.x;
      As[ac4 * 4 + 1][m] = av.y;
      As[ac4 * 4 + 2][m] = av.z;
      As[ac4 * 4 + 3][m] = av.w;
    }
#pragma unroll
    for (int rr = 0; rr < 2; rr++) {
      int kk = brow + rr * 16;
      *reinterpret_cast<float4*>(&Bs[kk][bc4 * 4]) =
          *reinterpret_cast<const float4*>(&W[(size_t)(kb + kk) * CDIM + n0 + bc4 * 4]);
    }
    __syncthreads();
#pragma unroll
    for (int k = 0; k < 32; k++) {
      float4 a0 = *reinterpret_cast<const float4*>(&As[k][r * 8]);
      float4 a1 = *reinterpret_cast<const float4*>(&As[k][r * 8 + 4]);
      float4 b  = *reinterpret_cast<const float4*>(&Bs[k][c * 4]);
      float am[8] = {a0.x, a0.y, a0.z, a0.w, a1.x, a1.y, a1.z, a1.w};
      float bn[4] = {b.x, b.y, b.z, b.w};
#pragma unroll
      for (int i = 0; i < 8; i++)
#pragma unroll
        for (int j = 0; j < 4; j++) acc[i][j] += am[i] * bn[j];
    }
    __syncthreads();
  }
  const int head = n0 >> 6;
  if (blockIdx.z == 0) {
    // qk path: f32 (for hash, bitwise-identical), planes + invn (for attn)
#pragma unroll
    for (int ii = 0; ii < 8; ii++) {
      int m = m0 + r * 8 + ii;
      int b = m >> 12, t = m & 4095;
      size_t base = ((size_t)(b * 8 + head) * LSEQ + t) * DHD;
      float4 ov = {acc[ii][0], acc[ii][1], acc[ii][2], acc[ii][3]};
      *reinterpret_cast<float4*>(&qk[base + c * 4]) = ov;
      uint32_t h0, l0, h1, l1, h2, l2, h3, l3;
      split2(ov.x, h0, l0); split2(ov.y, h1, l1);
      split2(ov.z, h2, l2); split2(ov.w, h3, l3);
      uint2 hw = {(h1 << 16) | h0, (h3 << 16) | h2};
      uint2 lw = {(l1 << 16) | l0, (l3 << 16) | l2};
      *reinterpret_cast<uint2*>(&qkhi[base + c * 4]) = hw;
      *reinterpret_cast<uint2*>(&qklo[base + c * 4]) = lw;
      float ss = ov.x * ov.x + ov.y * ov.y + ov.z * ov.z + ov.w * ov.w;
      ss += __shfl_xor(ss, 1, 64);
      ss += __shfl_xor(ss, 2, 64);
      ss += __shfl_xor(ss, 4, 64);
      ss += __shfl_xor(ss, 8, 64);
      if (c == 0)
        invn_g[(size_t)(b * 8 + head) * LSEQ + t] = 1.0f / fmaxf(sqrtf(ss), 1e-12f);
    }
  } else {
    // v path: bf16 hi plane only
#pragma unroll
    for (int ii = 0; ii < 8; ii++) {
      int m = m0 + r * 8 + ii;
      int b = m >> 12, t = m & 4095;
      size_t base = ((size_t)(b * 8 + head) * LSEQ + t) * DHD;
      uint32_t h0 = f2bf(acc[ii][0]), h1 = f2bf(acc[ii][1]);
      uint32_t h2 = f2bf(acc[ii][2]), h3 = f2bf(acc[ii][3]);
      uint2 hw = {(h1 << 16) | h0, (h3 << 16) | h2};
      *reinterpret_cast<uint2*>(&vhi[base + c * 4]) = hw;
    }
  }
}

// ---------------------------------------------------------------------------
// K2: LSH hashing.  UNCHANGED (bucket determinism; reads f32 qk).
// ---------------------------------------------------------------------------
__global__ __launch_bounds__(256) void hash_kernel(
    const float* __restrict__ qk, const float* __restrict__ rot,
    int* __restrict__ buckets)
{
  __shared__ float rotT[128][68];   // [h*32+i][f]
  const int tid = threadIdx.x;
  for (int idx = tid; idx < 64 * 128; idx += 256) {
    int f = idx >> 7, hi = idx & 127;
    rotT[hi][f] = rot[idx];
  }
  __syncthreads();
  const int bh = blockIdx.y;
  const int t = blockIdx.x * 256 + tid;
  float4 row4[16];
  const float* src = &qk[((size_t)bh * LSEQ + t) * DHD];
#pragma unroll
  for (int i = 0; i < 16; i++) row4[i] = reinterpret_cast<const float4*>(src)[i];

  int* bout = &buckets[(size_t)bh * NHASH * LSEQ];
  for (int h = 0; h < NHASH; h++) {
    float rc[32];
    float best = -3.0e38f;
    int bidx = 0;
#pragma unroll 4
    for (int i = 0; i < 32; i++) {
      const float* rr = &rotT[h * 32 + i][0];
      float a = 0.f;
#pragma unroll
      for (int f4 = 0; f4 < 16; f4++) {
        float4 rv = reinterpret_cast<const float4*>(rr)[f4];
        a += row4[f4].x * rv.x + row4[f4].y * rv.y + row4[f4].z * rv.z + row4[f4].w * rv.w;
      }
      rc[i] = a;
      if (a > best) { best = a; bidx = i; }
    }
#pragma unroll
    for (int i = 0; i < 32; i++) {
      float nv = -rc[i];
      if (nv > best) { best = nv; bidx = 32 + i; }
    }
    bout[h * LSEQ + t] = bidx;
  }
}

// ---------------------------------------------------------------------------
// K3: stable counting sort per (bh, h).  UNCHANGED.
// ---------------------------------------------------------------------------
__global__ __launch_bounds__(256) void sort_kernel(
    const int* __restrict__ buckets, int* __restrict__ st)
{
  __shared__ int hist[64][64];
  const int h = blockIdx.x, bh = blockIdx.y;
  const int tid = threadIdx.x;
  const int* bk = &buckets[((size_t)bh * NHASH + h) * LSEQ];

  for (int i = tid; i < 64 * 64; i += 256) (&hist[0][0])[i] = 0;
  __syncthreads();
  for (int t = tid; t < LSEQ; t += 256) {
    int b = bk[t];
    atomicAdd(&hist[t >> 6][b], 1);
  }
  __syncthreads();
  if (tid < 64) {
    int tot = 0;
    for (int s = 0; s < 64; s++) tot += hist[s][tid];
    int vsc = tot;
    for (int off = 1; off < 64; off <<= 1) {
      int nv = __shfl_up(vsc, off, 64);
      if (tid >= off) vsc += nv;
    }
    int run = h * LSEQ + (vsc - tot);
    for (int s = 0; s < 64; s++) {
      int tmp = hist[s][tid];
      hist[s][tid] = run;
      run += tmp;
    }
  }
  __syncthreads();
  const int wave = tid >> 6, lane = tid & 63;
  for (int si = 0; si < 16; si++) {
    int seg = wave * 16 + si;
    int pos = seg * 64 + lane;
    int b = bk[pos];
    int rank = 0;
    for (int k = 0; k < 64; k++) {
      int bb = __shfl(b, k, 64);
      rank += (bb == b && k < lane) ? 1 : 0;
    }
    int dest = hist[seg][b] + rank;
    st[(size_t)bh * (NHASH * LSEQ) + dest] = pos;
  }
}

// ---------------------------------------------------------------------------
// K4: chunked attention, v4.  Pre-split planes from global; zero split VALU
// in staging.  LDS 52 KB -> 3 blocks/CU.
//  Khi/Klo [128][68] u16 (b64 frags); Vthi [64][128] u16 XOR-swizzled
//  (chunk c' = c ^ (d&15)); P32 [64][132] u32 aliases K planes.
//  QK^T = 3-term bf16 split (identical math to round 3); PV = 2-term
//  (ph+pl)*vhi; O stored bf16.
// ---------------------------------------------------------------------------
__global__ __launch_bounds__(256) void attn_kernel(
    const uint16_t* __restrict__ qkhi, const uint16_t* __restrict__ qklo,
    const uint16_t* __restrict__ vhi, const float* __restrict__ invn_g,
    const int* __restrict__ st, uint16_t* __restrict__ o,
    float* __restrict__ lse_out)
{
  __shared__ __align__(16) uint8_t smem[53248];
  uint16_t* Khi  = (uint16_t*)smem;                  // [128][68] = 17408 B
  uint16_t* Klo  = Khi + 128 * 68;                   // +17408 B
  uint16_t* Vthi = (uint16_t*)(smem + 34816);        // [64][128] = 16384 B
  float*    invn = (float*)(smem + 52224);           // 128 f
  int*      kpos = (int*)(smem + 52736);             // 128 i
  uint32_t* P32  = (uint32_t*)smem;                  // [64][132] u32, alias K

  const int cchunk = blockIdx.x, bh = blockIdx.y;
  const int tid = threadIdx.x;
  const int prev = (cchunk + NCHUNK - 1) & (NCHUNK - 1);
  const int* stb = &st[(size_t)bh * (NHASH * LSEQ)];
  const int h = cchunk >> 6;

  if (tid < 128) {
    int kp = (tid < 64) ? stb[prev * 64 + tid] : stb[cchunk * 64 + (tid - 64)];
    kpos[tid] = kp;
    invn[tid] = invn_g[(size_t)bh * LSEQ + kp];
  }
  __syncthreads();

  // ---- stage K planes (pure copies) ----
  {
    const int d4 = tid & 15, rbase = tid >> 4;
    const uint16_t* qhb = qkhi + (size_t)bh * LSEQ * DHD;
    const uint16_t* qlb = qklo + (size_t)bh * LSEQ * DHD;
#pragma unroll
    for (int it = 0; it < 8; it++) {
      int row = rbase + it * 16;
      size_t src = (size_t)kpos[row] * DHD + d4 * 4;
      *reinterpret_cast<uint2*>(Khi + row * 68 + d4 * 4) =
          *reinterpret_cast<const uint2*>(qhb + src);
      *reinterpret_cast<uint2*>(Klo + row * 68 + d4 * 4) =
          *reinterpret_cast<const uint2*>(qlb + src);
    }
  }
  // ---- stage V transposed (u16 4x4 transpose), swizzled ----
  {
    const int d4 = tid & 15, jg0 = tid >> 4;
    const uint16_t* vb = vhi + (size_t)bh * LSEQ * DHD;
#pragma unroll
    for (int half = 0; half < 2; half++) {
      int jg = jg0 + half * 16;   // 0..31, j = 4*jg..4*jg+3
      uint2 vr[4];
#pragma unroll
      for (int s = 0; s < 4; s++)
        vr[s] = *reinterpret_cast<const uint2*>(vb + (size_t)kpos[jg * 4 + s] * DHD + d4 * 4);
#pragma unroll
      for (int i = 0; i < 4; i++) {
        int d = d4 * 4 + i;
        uint32_t e0 = (((i & 2) ? vr[0].y : vr[0].x) >> ((i & 1) * 16)) & 0xffffu;
        uint32_t e1 = (((i & 2) ? vr[1].y : vr[1].x) >> ((i & 1) * 16)) & 0xffffu;
        uint32_t e2 = (((i & 2) ? vr[2].y : vr[2].x) >> ((i & 1) * 16)) & 0xffffu;
        uint32_t e3 = (((i & 2) ? vr[3].y : vr[3].x) >> ((i & 1) * 16)) & 0xffffu;
        uint2 outw = {e0 | (e1 << 16), e2 | (e3 << 16)};
        int cpr = (jg >> 1) ^ (d & 15);
        *reinterpret_cast<uint2*>(Vthi + d * 128 + cpr * 8 + (jg & 1) * 4) = outw;
      }
    }
  }
  __syncthreads();

  const int lane = tid & 63, w = tid >> 6;
  const int l16 = lane & 15, lg = lane >> 4;

  // ---- QK^T (bf16x3), wave w -> q-rows 16w..16w+15 ----
  f32x4 acc[8];
#pragma unroll
  for (int nt = 0; nt < 8; nt++) acc[nt] = {0.f, 0.f, 0.f, 0.f};

#pragma unroll
  for (int ks = 0; ks < 2; ks++) {
    int aoff = (64 + w * 16 + l16) * 68 + ks * 32 + lg * 8;
    short8 a_hi = ldsK(Khi + aoff);
    short8 a_lo = ldsK(Klo + aoff);
#pragma unroll
    for (int nt = 0; nt < 8; nt++) {
      int boff = (nt * 16 + l16) * 68 + ks * 32 + lg * 8;
      short8 b_hi = ldsK(Khi + boff);
      short8 b_lo = ldsK(Klo + boff);
      acc[nt] = __builtin_amdgcn_mfma_f32_16x16x32_bf16(a_hi, b_hi, acc[nt], 0, 0, 0);
      acc[nt] = __builtin_amdgcn_mfma_f32_16x16x32_bf16(a_lo, b_hi, acc[nt], 0, 0, 0);
      acc[nt] = __builtin_amdgcn_mfma_f32_16x16x32_bf16(a_hi, b_lo, acc[nt], 0, 0, 0);
    }
  }

  // ---- register softmax on the D-layout ----
  float invc[8]; int kpc[8];
#pragma unroll
  for (int nt = 0; nt < 8; nt++) {
    invc[nt] = invn[nt * 16 + l16] * 0.125f;
    kpc[nt] = kpos[nt * 16 + l16];
  }
  float pll[4];
#pragma unroll
  for (int r = 0; r < 4; r++) {
    int q = w * 16 + lg * 4 + r;
    int qp = kpos[64 + q];
    float mm = -3.0e38f;
#pragma unroll
    for (int nt = 0; nt < 8; nt++) {
      float s = acc[nt][r] * invc[nt];
      if (qp == kpc[nt]) s = -5e4f;
      acc[nt][r] = s;
      mm = fmaxf(mm, s);
    }
    mm = fmaxf(mm, __shfl_xor(mm, 1, 64));
    mm = fmaxf(mm, __shfl_xor(mm, 2, 64));
    mm = fmaxf(mm, __shfl_xor(mm, 4, 64));
    mm = fmaxf(mm, __shfl_xor(mm, 8, 64));
    float ll = 0.f;
#pragma unroll
    for (int nt = 0; nt < 8; nt++) {
      float p = __expf(acc[nt][r] - mm);
      acc[nt][r] = p;
      ll += p;
    }
    ll += __shfl_xor(ll, 1, 64);
    ll += __shfl_xor(ll, 2, 64);
    ll += __shfl_xor(ll, 4, 64);
    ll += __shfl_xor(ll, 8, 64);
    if (l16 == 0)
      lse_out[(size_t)bh * (NHASH * LSEQ) + h * LSEQ + qp] = mm + __logf(ll);
    pll[r] = 1.0f / ll;
  }
  __syncthreads();   // all K-plane reads done; safe to alias P32

  // ---- write P (packed hi|lo u32) ----
#pragma unroll
  for (int r = 0; r < 4; r++) {
    int q = w * 16 + lg * 4 + r;
#pragma unroll
    for (int nt = 0; nt < 8; nt++) {
      uint32_t phi, plo;
      split2(acc[nt][r], phi, plo);
      P32[q * 132 + nt * 16 + l16] = (plo << 16) | phi;
    }
  }
  // no barrier: wave reads back only its own 16 P rows

  // ---- PV: O = P.Vhi (2-term) ----
  f32x4 oacc[4];
#pragma unroll
  for (int nt = 0; nt < 4; nt++) oacc[nt] = {0.f, 0.f, 0.f, 0.f};

#pragma unroll
  for (int ks = 0; ks < 4; ks++) {
    const uint32_t* pr = P32 + (w * 16 + l16) * 132 + ks * 32 + lg * 8;
    uint4 ua = *reinterpret_cast<const uint4*>(pr);
    uint4 ub = *reinterpret_cast<const uint4*>(pr + 4);
    uint32_t u[8] = {ua.x, ua.y, ua.z, ua.w, ub.x, ub.y, ub.z, ub.w};
    union { uint32_t w4[4]; short8 s8; } ph, pl;
#pragma unroll
    for (int k2 = 0; k2 < 4; k2++) {
      ph.w4[k2] = (u[2 * k2] & 0xffffu) | (u[2 * k2 + 1] << 16);
      pl.w4[k2] = (u[2 * k2] >> 16) | (u[2 * k2 + 1] & 0xffff0000u);
    }
    const int cc = ks * 4 + lg;
#pragma unroll
    for (int nt = 0; nt < 4; nt++) {
      int voff = (nt * 16 + l16) * 128 + ((cc ^ l16) & 15) * 8;
      short8 v_hi = *reinterpret_cast<const short8*>(Vthi + voff);
      oacc[nt] = __builtin_amdgcn_mfma_f32_16x16x32_bf16(ph.s8, v_hi, oacc[nt], 0, 0, 0);
      oacc[nt] = __builtin_amdgcn_mfma_f32_16x16x32_bf16(pl.s8, v_hi, oacc[nt], 0, 0, 0);
    }
  }

  // ---- normalize + write O (bf16, unsorted) ----
  {
    uint16_t* ob = o + ((size_t)bh * (NHASH * LSEQ) + (size_t)h * LSEQ) * DHD;
#pragma unroll
    for (int r = 0; r < 4; r++) {
      int q = w * 16 + lg * 4 + r;
      int qp = kpos[64 + q];
      float s = pll[r];
#pragma unroll
      for (int nt = 0; nt < 4; nt++)
        ob[(size_t)qp * DHD + nt * 16 + l16] = (uint16_t)f2bf(oacc[nt][r] * s);
    }
  }
}

// ---------------------------------------------------------------------------
// K5: combine hash rounds -> comb bf16 hi/lo planes.  grid 32768, block 256.
// ---------------------------------------------------------------------------
__global__ __launch_bounds__(256) void combine_kernel(
    const uint16_t* __restrict__ o, const float* __restrict__ lse,
    uint16_t* __restrict__ comb_hi, uint16_t* __restrict__ comb_lo)
{
  int gid = blockIdx.x * 4 + (threadIdx.x >> 6);
  int lane = threadIdx.x & 63;
  int bh = gid >> 12;
  int pos = gid & 4095;
  const float* lb = &lse[(size_t)bh * (NHASH * LSEQ) + pos];
  float l0 = lb[0], l1 = lb[LSEQ], l2 = lb[2 * LSEQ], l3 = lb[3 * LSEQ];
  float m = fmaxf(fmaxf(l0, l1), fmaxf(l2, l3));
  float w0 = __expf(l0 - m), w1 = __expf(l1 - m), w2 = __expf(l2 - m), w3 = __expf(l3 - m);
  float inv = 1.0f / (w0 + w1 + w2 + w3);
  const uint16_t* ob = &o[((size_t)bh * (NHASH * LSEQ) + pos) * DHD];
  float val = (w0 * bf2f(ob[lane]) + w1 * bf2f(ob[(size_t)LSEQ * DHD + lane]) +
               w2 * bf2f(ob[(size_t)2 * LSEQ * DHD + lane]) +
               w3 * bf2f(ob[(size_t)3 * LSEQ * DHD + lane])) * inv;
  int b = bh >> 3, head = bh & 7;
  size_t idx = ((size_t)(b * LSEQ + pos)) * CDIM + head * DHD + lane;
  uint32_t hi, lo;
  split2(val, hi, lo);
  comb_hi[idx] = (uint16_t)hi;
  comb_lo[idx] = (uint16_t)lo;
}

// ---------------------------------------------------------------------------
// K5b: Wo prep — split + transpose to woT[n][k] bf16 planes.  grid 1024.
// ---------------------------------------------------------------------------
__global__ __launch_bounds__(256) void prep_wo_kernel(
    const float* __restrict__ Wo, uint16_t* __restrict__ th,
    uint16_t* __restrict__ tl)
{
  int idx = blockIdx.x * 256 + threadIdx.x;   // k*512 + n
  int k = idx >> 9, n = idx & 511;
  uint32_t hi, lo;
  split2(Wo[idx], hi, lo);
  th[n * 512 + k] = (uint16_t)hi;
  tl[n * 512 + k] = (uint16_t)lo;
}

// ---------------------------------------------------------------------------
// K6: output GEMM, bf16x3 MFMA.  comb(16384x512) @ Wo + bo -> out f32.
// grid (128, 4), block 256 (4 waves = 2x2 quadrants of 64x64).
// Tiles [128][40] u16 (80 B rows: 16B-aligned, 2-way-free b128 frags).
// ---------------------------------------------------------------------------
__global__ __launch_bounds__(256) void gemm_out_kernel(
    const uint16_t* __restrict__ Ahi_g, const uint16_t* __restrict__ Alo_g,
    const uint16_t* __restrict__ Bhi_g, const uint16_t* __restrict__ Blo_g,
    const float* __restrict__ bias, float* __restrict__ out)
{
  __shared__ __align__(16) uint16_t Ah[128 * 40];
  __shared__ __align__(16) uint16_t Al[128 * 40];
  __shared__ __align__(16) uint16_t Bh[128 * 40];
  __shared__ __align__(16) uint16_t Bl[128 * 40];
  const int tid = threadIdx.x;
  const int m0 = blockIdx.x * 128, n0 = blockIdx.y * 128;
  const int lane = tid & 63, w = tid >> 6;
  const int l16 = lane & 15, lg = lane >> 4;
  const int mq = w >> 1, nq = w & 1;
  f32x4 acc[4][4];
#pragma unroll
  for (int i = 0; i < 4; i++)
#pragma unroll
    for (int j = 0; j < 4; j++) acc[i][j] = {0.f, 0.f, 0.f, 0.f};

  const int srow = tid >> 1, sh = tid & 1;
  for (int kb = 0; kb < CDIM; kb += 32) {
    {
      const uint4* sa_h = (const uint4*)(Ahi_g + (size_t)(m0 + srow) * CDIM + kb + sh * 16);
      const uint4* sa_l = (const uint4*)(Alo_g + (size_t)(m0 + srow) * CDIM + kb + sh * 16);
      const uint4* sb_h = (const uint4*)(Bhi_g + (size_t)(n0 + srow) * CDIM + kb + sh * 16);
      const uint4* sb_l = (const uint4*)(Blo_g + (size_t)(n0 + srow) * CDIM + kb + sh * 16);
      uint4* da_h = (uint4*)(Ah + srow * 40 + sh * 16);
      uint4* da_l = (uint4*)(Al + srow * 40 + sh * 16);
      uint4* db_h = (uint4*)(Bh + srow * 40 + sh * 16);
      uint4* db_l = (uint4*)(Bl + srow * 40 + sh * 16);
      da_h[0] = sa_h[0]; da_h[1] = sa_h[1];
      da_l[0] = sa_l[0]; da_l[1] = sa_l[1];
      db_h[0] = sb_h[0]; db_h[1] = sb_h[1];
      db_l[0] = sb_l[0]; db_l[1] = sb_l[1];
    }
    __syncthreads();
    short8 fa_h[4], fa_l[4], fb_h[4], fb_l[4];
#pragma unroll
    for (int mt = 0; mt < 4; mt++) {
      int ao = (mq * 64 + mt * 16 + l16) * 40 + lg * 8;
      fa_h[mt] = *reinterpret_cast<const short8*>(Ah + ao);
      fa_l[mt] = *reinterpret_cast<const short8*>(Al + ao);
    }
#pragma unroll
    for (int nt = 0; nt < 4; nt++) {
      int bo_ = (nq * 64 + nt * 16 + l16) * 40 + lg * 8;
      fb_h[nt] = *reinterpret_cast<const short8*>(Bh + bo_);
      fb_l[nt] = *reinterpret_cast<const short8*>(Bl + bo_);
    }
#pragma unroll
    for (int mt = 0; mt < 4; mt++)
#pragma unroll
      for (int nt = 0; nt < 4; nt++) {
        acc[mt][nt] = __builtin_amdgcn_mfma_f32_16x16x32_bf16(fa_h[mt], fb_h[nt], acc[mt][nt], 0, 0, 0);
        acc[mt][nt] = __builtin_amdgcn_mfma_f32_16x16x32_bf16(fa_l[mt], fb_h[nt], acc[mt][nt], 0, 0, 0);
        acc[mt][nt] = __builtin_amdgcn_mfma_f32_16x16x32_bf16(fa_h[mt], fb_l[nt], acc[mt][nt], 0, 0, 0);
      }
    __syncthreads();
  }
#pragma unroll
  for (int nt = 0; nt < 4; nt++) {
    int n = n0 + nq * 64 + nt * 16 + l16;
    float bv = bias[n];
#pragma unroll
    for (int mt = 0; mt < 4; mt++) {
#pragma unroll
      for (int rr = 0; rr < 4; rr++) {
        int m = m0 + mq * 64 + mt * 16 + lg * 4 + rr;
        out[(size_t)m * CDIM + n] = acc[mt][nt][rr] + bv;
      }
    }
  }
}

// ---------------------------------------------------------------------------
extern "C" void kernel_launch(void* const* d_in, const int* in_sizes, int n_in,
                              void* d_out, int out_size, void* d_ws, size_t ws_size,
                              hipStream_t stream) {
  (void)in_sizes; (void)n_in; (void)out_size; (void)ws_size;
  const float* X    = (const float*)d_in[0];   // queries (4,4096,512)
  const float* Wqk  = (const float*)d_in[6];
  const float* Wv   = (const float*)d_in[7];
  const float* Wo   = (const float*)d_in[8];
  const float* bo   = (const float*)d_in[9];
  const float* rot  = (const float*)d_in[10];  // (64, 4, 32)

  // workspace layout (bytes), total ~151.5 MB
  uint8_t* W = (uint8_t*)d_ws;
  float*    qk      = (float*)(W + 0);              // 33,554,432 B
  uint16_t* obuf    = (uint16_t*)(W + 33554432);    // 67,108,864 B
  uint16_t* qkhi    = (uint16_t*)(W + 100663296);   // 16,777,216 B
  uint16_t* qklo    = (uint16_t*)(W + 117440512);   // 16,777,216 B
  uint16_t* vhi     = (uint16_t*)(W + 134217728);   // 16,777,216 B
  int*      buckets = (int*)(W + 150994944);        //  2,097,152 B
  int*      st      = (int*)(W + 153092096);        //  2,097,152 B
  float*    lse     = (float*)(W + 155189248);      //  2,097,152 B
  float*    invn_g  = (float*)(W + 157286400);      //    524,288 B
  uint16_t* woT_hi  = (uint16_t*)(W + 157810688);   //    524,288 B
  uint16_t* woT_lo  = (uint16_t*)(W + 158334976);   //    524,288 B
  uint16_t* comb_hi = (uint16_t*)(W + 0);           // alias qk (dead post-hash)
  uint16_t* comb_lo = (uint16_t*)(W + 16777216);

  hipLaunchKernelGGL(gemm_in_kernel, dim3(128, 8, 2), dim3(256), 0, stream,
                     X, Wqk, Wv, qk, qkhi, qklo, vhi, invn_g);
  hipLaunchKernelGGL(hash_kernel, dim3(16, 32), dim3(256), 0, stream,
                     qk, rot, buckets);
  hipLaunchKernelGGL(sort_kernel, dim3(4, 32), dim3(256), 0, stream,
                     buckets, st);
  hipLaunchKernelGGL(prep_wo_kernel, dim3(1024), dim3(256), 0, stream,
                     Wo, woT_hi, woT_lo);
  hipLaunchKernelGGL(attn_kernel, dim3(256, 32), dim3(256), 0, stream,
                     qkhi, qklo, vhi, invn_g, st, obuf, lse);
  hipLaunchKernelGGL(combine_kernel, dim3(32768), dim3(256), 0, stream,
                     obuf, lse, comb_hi, comb_lo);
  hipLaunchKernelGGL(gemm_out_kernel, dim3(128, 4), dim3(256), 0, stream,
                     comb_hi, comb_lo, woT_hi, woT_lo, bo, (float*)d_out);
}

// Round 6
// 460.100 us; speedup vs baseline: 2.0629x; 1.1181x over previous
//
#include <hip/hip_runtime.h>
#include <hip/hip_bf16.h>
#include <cstdint>
#include <cstddef>

// Problem constants (fixed by setup_inputs)
#define LSEQ   4096
#define DHD    64
#define NHASH  4
#define CDIM   512
#define NBH    32        // B*HEADS
#define MROWS  16384     // B*LSEQ
#define NCHUNK 256       // NHASH*LSEQ/64

typedef __attribute__((ext_vector_type(8))) short short8;
typedef __attribute__((ext_vector_type(4))) float f32x4;
typedef __attribute__((ext_vector_type(2))) float f32x2;

__device__ inline uint32_t f2bf(float f) {
  uint32_t u = __float_as_uint(f);
  return (u + 0x7FFFu + ((u >> 16) & 1u)) >> 16;
}
__device__ inline float bf2f(uint32_t h) { return __uint_as_float(h << 16); }
__device__ inline void split2(float f, uint32_t& hi, uint32_t& lo) {
  hi = f2bf(f);
  lo = f2bf(f - bf2f(hi));
}
__device__ inline short8 ldsK(const uint16_t* p) {   // two b64 reads -> short8
  union { uint2 u[2]; short8 s; } t;
  t.u[0] = *reinterpret_cast<const uint2*>(p);
  t.u[1] = *reinterpret_cast<const uint2*>(p + 4);
  return t.s;
}

// ---------------------------------------------------------------------------
// K0a: split X into 2 bf16 planes (hi/mid) for the v MFMA path.
// ---------------------------------------------------------------------------
__global__ __launch_bounds__(256) void prep_x_kernel(
    const float* __restrict__ X, uint16_t* __restrict__ X0,
    uint16_t* __restrict__ X1)
{
  size_t i = ((size_t)blockIdx.x * 256 + threadIdx.x) * 4;
  float4 v = *reinterpret_cast<const float4*>(X + i);
  uint32_t h[4], l[4];
#pragma unroll
  for (int j = 0; j < 4; j++) split2((&v.x)[j], h[j], l[j]);
  uint2 hw = {(h[1] << 16) | h[0], (h[3] << 16) | h[2]};
  uint2 lw = {(l[1] << 16) | l[0], (l[3] << 16) | l[2]};
  *reinterpret_cast<uint2*>(X0 + i) = hw;
  *reinterpret_cast<uint2*>(X1 + i) = lw;
}

// ---------------------------------------------------------------------------
// K0b: transpose + 2-way split Wv -> Wv^T[n][k] bf16 planes.  grid (16,16).
// ---------------------------------------------------------------------------
__global__ __launch_bounds__(256) void prep_wv_kernel(
    const float* __restrict__ Wv,
    uint16_t* __restrict__ v0, uint16_t* __restrict__ v1)
{
  __shared__ float Ts[32][33];
  const int tid = threadIdx.x;
  const int k0 = blockIdx.x * 32, n0 = blockIdx.y * 32;
#pragma unroll
  for (int i = 0; i < 4; i++) {
    int flat = i * 256 + tid;
    int r = flat >> 5, c = flat & 31;
    Ts[r][c] = Wv[(size_t)(k0 + r) * 512 + n0 + c];
  }
  __syncthreads();
#pragma unroll
  for (int i = 0; i < 4; i++) {
    int flat = i * 256 + tid;
    int nr = flat >> 5, kc = flat & 31;
    uint32_t h, l;
    split2(Ts[kc][nr], h, l);
    size_t idx = (size_t)(n0 + nr) * 512 + k0 + kc;
    v0[idx] = (uint16_t)h;
    v1[idx] = (uint16_t)l;
  }
}

// ---------------------------------------------------------------------------
// K1a: qk projection GEMM — FROZEN MATH (bitwise-identical to the r1-r4
// passing kernel: same staging copies, same k-ascending fused-FMA chain per
// output element).  Only change: accumulators held as float2 pairs so the
// backend can select v_pk_fma_f32 — per-component the chain is the same
// llvm.fmuladd sequence, bitwise-identical either way.
// grid (128, 8), block 256.  Epilogue = r4's z=0 epilogue (qk f32 + bf16
// hi/lo planes + invn).
// ---------------------------------------------------------------------------
__global__ __launch_bounds__(256) void gemm_qk_kernel(
    const float* __restrict__ X, const float* __restrict__ Wqk,
    float* __restrict__ qk, uint16_t* __restrict__ qkhi,
    uint16_t* __restrict__ qklo, float* __restrict__ invn_g)
{
  const float* W = Wqk;
  const int m0 = blockIdx.x * 128;
  const int n0 = blockIdx.y * 64;
  __shared__ float As[32][132];   // [k][m] transposed
  __shared__ float Bs[32][68];    // [k][n]
  const int tid = threadIdx.x;
  const int r = tid >> 4, c = tid & 15;   // rows 8r..8r+7, cols 4c..4c+3
  f32x2 acc2[8][2];
#pragma unroll
  for (int i = 0; i < 8; i++) {
    acc2[i][0] = {0.f, 0.f};
    acc2[i][1] = {0.f, 0.f};
  }

  const int arow = tid >> 3;   // 0..31
  const int ac4  = tid & 7;    // k-chunk
  const int brow = tid >> 4;   // 0..15
  const int bc4  = tid & 15;

  for (int kb = 0; kb < CDIM; kb += 32) {
    // stage A (transposed) — exact element copies
#pragma unroll
    for (int rr = 0; rr < 4; rr++) {
      int m = arow + rr * 32;
      float4 av = *reinterpret_cast<const float4*>(&X[(size_t)(m0 + m) * CDIM + kb + ac4 * 4]);
      As[ac4 * 4 + 0][m] = av.x;
      As[ac4 * 4 + 1][m] = av.y;
      As[ac4 * 4 + 2][m] = av.z;
      As[ac4 * 4 + 3][m] = av.w;
    }
    // stage B
#pragma unroll
    for (int rr = 0; rr < 2; rr++) {
      int kk = brow + rr * 16;
      *reinterpret_cast<float4*>(&Bs[kk][bc4 * 4]) =
          *reinterpret_cast<const float4*>(&W[(size_t)(kb + kk) * CDIM + n0 + bc4 * 4]);
    }
    __syncthreads();
#pragma unroll
    for (int k = 0; k < 32; k++) {
      float4 a0 = *reinterpret_cast<const float4*>(&As[k][r * 8]);
      float4 a1 = *reinterpret_cast<const float4*>(&As[k][r * 8 + 4]);
      float4 b  = *reinterpret_cast<const float4*>(&Bs[k][c * 4]);
      float am[8] = {a0.x, a0.y, a0.z, a0.w, a1.x, a1.y, a1.z, a1.w};
      f32x2 b01 = {b.x, b.y};
      f32x2 b23 = {b.z, b.w};
#pragma unroll
      for (int i = 0; i < 8; i++) {
        f32x2 av = {am[i], am[i]};
        acc2[i][0] += av * b01;   // fmuladd per component, k-ascending chain
        acc2[i][1] += av * b23;
      }
    }
    __syncthreads();
  }
  // epilogue (identical to r4): qk f32 + hi/lo planes + invn
  const int head = n0 >> 6;
#pragma unroll
  for (int ii = 0; ii < 8; ii++) {
    int m = m0 + r * 8 + ii;
    int b = m >> 12, t = m & 4095;
    size_t base = ((size_t)(b * 8 + head) * LSEQ + t) * DHD;
    float4 ov = {acc2[ii][0][0], acc2[ii][0][1], acc2[ii][1][0], acc2[ii][1][1]};
    *reinterpret_cast<float4*>(&qk[base + c * 4]) = ov;
    uint32_t h0, l0, h1, l1, h2, l2, h3, l3;
    split2(ov.x, h0, l0); split2(ov.y, h1, l1);
    split2(ov.z, h2, l2); split2(ov.w, h3, l3);
    uint2 hw = {(h1 << 16) | h0, (h3 << 16) | h2};
    uint2 lw = {(l1 << 16) | l0, (l3 << 16) | l2};
    *reinterpret_cast<uint2*>(&qkhi[base + c * 4]) = hw;
    *reinterpret_cast<uint2*>(&qklo[base + c * 4]) = lw;
    float ss = ov.x * ov.x + ov.y * ov.y + ov.z * ov.z + ov.w * ov.w;
    ss += __shfl_xor(ss, 1, 64);
    ss += __shfl_xor(ss, 2, 64);
    ss += __shfl_xor(ss, 4, 64);
    ss += __shfl_xor(ss, 8, 64);
    if (c == 0)
      invn_g[(size_t)(b * 8 + head) * LSEQ + t] = 1.0f / fmaxf(sqrtf(ss), 1e-12f);
  }
}

// ---------------------------------------------------------------------------
// K1b: v projection via bf16-split MFMA (3-term; v is consumed only as a
// bf16 plane so 2e-5 relative error is irrelevant; touches nothing discrete).
// grid (128, 4), block 512 (8 waves).  Tile 128x128, K-step 32.
// ---------------------------------------------------------------------------
__global__ __launch_bounds__(512) void gemm_v_mfma_kernel(
    const uint16_t* __restrict__ X0g, const uint16_t* __restrict__ X1g,
    const uint16_t* __restrict__ Wv0, const uint16_t* __restrict__ Wv1,
    uint16_t* __restrict__ vhi)
{
  __shared__ __align__(16) uint16_t Xs[2 * 128 * 40];
  __shared__ __align__(16) uint16_t Ws[2 * 128 * 40];
  const int tid = threadIdx.x;
  const int m0 = blockIdx.x * 128;
  const int n0 = blockIdx.y * 128;
  const int lane = tid & 63, w = tid >> 6;
  const int l16 = lane & 15, lg = lane >> 4;

  f32x4 acc[8];
#pragma unroll
  for (int nt = 0; nt < 8; nt++) acc[nt] = {0.f, 0.f, 0.f, 0.f};

  const int srow = tid >> 3;          // 0..63
  const int sch = (tid & 7) * 4;      // u16 offset within 32-k row

  for (int kb = 0; kb < CDIM; kb += 32) {
#pragma unroll
    for (int i = 0; i < 4; i++) {
      int p = i >> 1;
      int row = (i & 1) * 64 + srow;
      const uint16_t* xg = (p == 0) ? X0g : X1g;
      const uint16_t* wg = (p == 0) ? Wv0 : Wv1;
      *reinterpret_cast<uint2*>(Xs + p * 5120 + row * 40 + sch) =
          *reinterpret_cast<const uint2*>(xg + (size_t)(m0 + row) * 512 + kb + sch);
      *reinterpret_cast<uint2*>(Ws + p * 5120 + row * 40 + sch) =
          *reinterpret_cast<const uint2*>(wg + (size_t)(n0 + row) * 512 + kb + sch);
    }
    __syncthreads();

    const int abase = (w * 16 + l16) * 40 + lg * 8;
    short8 a0 = *reinterpret_cast<const short8*>(Xs + abase);
    short8 a1 = *reinterpret_cast<const short8*>(Xs + 5120 + abase);
#pragma unroll
    for (int nt = 0; nt < 8; nt++) {
      int bbase = (nt * 16 + l16) * 40 + lg * 8;
      short8 b0 = *reinterpret_cast<const short8*>(Ws + bbase);
      short8 b1 = *reinterpret_cast<const short8*>(Ws + 5120 + bbase);
      acc[nt] = __builtin_amdgcn_mfma_f32_16x16x32_bf16(a0, b0, acc[nt], 0, 0, 0);
      acc[nt] = __builtin_amdgcn_mfma_f32_16x16x32_bf16(a1, b0, acc[nt], 0, 0, 0);
      acc[nt] = __builtin_amdgcn_mfma_f32_16x16x32_bf16(a0, b1, acc[nt], 0, 0, 0);
    }
    __syncthreads();
  }

#pragma unroll
  for (int rr = 0; rr < 4; rr++) {
    int mg = m0 + w * 16 + lg * 4 + rr;
    int b = mg >> 12, t = mg & 4095;
#pragma unroll
    for (int nt = 0; nt < 8; nt++) {
      int head = (n0 >> 6) + (nt >> 2);
      size_t base = ((size_t)(b * 8 + head) * LSEQ + t) * DHD + (nt & 3) * 16 + l16;
      vhi[base] = (uint16_t)f2bf(acc[nt][rr]);
    }
  }
}

// ---------------------------------------------------------------------------
// K2: LSH hashing.  UNCHANGED (bucket determinism; reads frozen f32 qk).
// ---------------------------------------------------------------------------
__global__ __launch_bounds__(256) void hash_kernel(
    const float* __restrict__ qk, const float* __restrict__ rot,
    int* __restrict__ buckets)
{
  __shared__ float rotT[128][68];   // [h*32+i][f]
  const int tid = threadIdx.x;
  for (int idx = tid; idx < 64 * 128; idx += 256) {
    int f = idx >> 7, hi = idx & 127;
    rotT[hi][f] = rot[idx];
  }
  __syncthreads();
  const int bh = blockIdx.y;
  const int t = blockIdx.x * 256 + tid;
  float4 row4[16];
  const float* src = &qk[((size_t)bh * LSEQ + t) * DHD];
#pragma unroll
  for (int i = 0; i < 16; i++) row4[i] = reinterpret_cast<const float4*>(src)[i];

  int* bout = &buckets[(size_t)bh * NHASH * LSEQ];
  for (int h = 0; h < NHASH; h++) {
    float rc[32];
    float best = -3.0e38f;
    int bidx = 0;
#pragma unroll 4
    for (int i = 0; i < 32; i++) {
      const float* rr = &rotT[h * 32 + i][0];
      float a = 0.f;
#pragma unroll
      for (int f4 = 0; f4 < 16; f4++) {
        float4 rv = reinterpret_cast<const float4*>(rr)[f4];
        a += row4[f4].x * rv.x + row4[f4].y * rv.y + row4[f4].z * rv.z + row4[f4].w * rv.w;
      }
      rc[i] = a;
      if (a > best) { best = a; bidx = i; }
    }
#pragma unroll
    for (int i = 0; i < 32; i++) {
      float nv = -rc[i];
      if (nv > best) { best = nv; bidx = 32 + i; }
    }
    bout[h * LSEQ + t] = bidx;
  }
}

// ---------------------------------------------------------------------------
// K3: stable counting sort per (bh, h).  UNCHANGED.
// ---------------------------------------------------------------------------
__global__ __launch_bounds__(256) void sort_kernel(
    const int* __restrict__ buckets, int* __restrict__ st)
{
  __shared__ int hist[64][64];
  const int h = blockIdx.x, bh = blockIdx.y;
  const int tid = threadIdx.x;
  const int* bk = &buckets[((size_t)bh * NHASH + h) * LSEQ];

  for (int i = tid; i < 64 * 64; i += 256) (&hist[0][0])[i] = 0;
  __syncthreads();
  for (int t = tid; t < LSEQ; t += 256) {
    int b = bk[t];
    atomicAdd(&hist[t >> 6][b], 1);
  }
  __syncthreads();
  if (tid < 64) {
    int tot = 0;
    for (int s = 0; s < 64; s++) tot += hist[s][tid];
    int vsc = tot;
    for (int off = 1; off < 64; off <<= 1) {
      int nv = __shfl_up(vsc, off, 64);
      if (tid >= off) vsc += nv;
    }
    int run = h * LSEQ + (vsc - tot);
    for (int s = 0; s < 64; s++) {
      int tmp = hist[s][tid];
      hist[s][tid] = run;
      run += tmp;
    }
  }
  __syncthreads();
  const int wave = tid >> 6, lane = tid & 63;
  for (int si = 0; si < 16; si++) {
    int seg = wave * 16 + si;
    int pos = seg * 64 + lane;
    int b = bk[pos];
    int rank = 0;
    for (int k = 0; k < 64; k++) {
      int bb = __shfl(b, k, 64);
      rank += (bb == b && k < lane) ? 1 : 0;
    }
    int dest = hist[seg][b] + rank;
    st[(size_t)bh * (NHASH * LSEQ) + dest] = pos;
  }
}

// ---------------------------------------------------------------------------
// K4: chunked attention (r4-passing version, UNCHANGED).
// ---------------------------------------------------------------------------
__global__ __launch_bounds__(256) void attn_kernel(
    const uint16_t* __restrict__ qkhi, const uint16_t* __restrict__ qklo,
    const uint16_t* __restrict__ vhi, const float* __restrict__ invn_g,
    const int* __restrict__ st, uint16_t* __restrict__ o,
    float* __restrict__ lse_out)
{
  __shared__ __align__(16) uint8_t smem[53248];
  uint16_t* Khi  = (uint16_t*)smem;                  // [128][68] = 17408 B
  uint16_t* Klo  = Khi + 128 * 68;                   // +17408 B
  uint16_t* Vthi = (uint16_t*)(smem + 34816);        // [64][128] = 16384 B
  float*    invn = (float*)(smem + 52224);           // 128 f
  int*      kpos = (int*)(smem + 52736);             // 128 i
  uint32_t* P32  = (uint32_t*)smem;                  // [64][132] u32, alias K

  const int cchunk = blockIdx.x, bh = blockIdx.y;
  const int tid = threadIdx.x;
  const int prev = (cchunk + NCHUNK - 1) & (NCHUNK - 1);
  const int* stb = &st[(size_t)bh * (NHASH * LSEQ)];
  const int h = cchunk >> 6;

  if (tid < 128) {
    int kp = (tid < 64) ? stb[prev * 64 + tid] : stb[cchunk * 64 + (tid - 64)];
    kpos[tid] = kp;
    invn[tid] = invn_g[(size_t)bh * LSEQ + kp];
  }
  __syncthreads();

  // ---- stage K planes (pure copies) ----
  {
    const int d4 = tid & 15, rbase = tid >> 4;
    const uint16_t* qhb = qkhi + (size_t)bh * LSEQ * DHD;
    const uint16_t* qlb = qklo + (size_t)bh * LSEQ * DHD;
#pragma unroll
    for (int it = 0; it < 8; it++) {
      int row = rbase + it * 16;
      size_t src = (size_t)kpos[row] * DHD + d4 * 4;
      *reinterpret_cast<uint2*>(Khi + row * 68 + d4 * 4) =
          *reinterpret_cast<const uint2*>(qhb + src);
      *reinterpret_cast<uint2*>(Klo + row * 68 + d4 * 4) =
          *reinterpret_cast<const uint2*>(qlb + src);
    }
  }
  // ---- stage V transposed (u16 4x4 transpose), swizzled ----
  {
    const int d4 = tid & 15, jg0 = tid >> 4;
    const uint16_t* vb = vhi + (size_t)bh * LSEQ * DHD;
#pragma unroll
    for (int half = 0; half < 2; half++) {
      int jg = jg0 + half * 16;   // 0..31, j = 4*jg..4*jg+3
      uint2 vr[4];
#pragma unroll
      for (int s = 0; s < 4; s++)
        vr[s] = *reinterpret_cast<const uint2*>(vb + (size_t)kpos[jg * 4 + s] * DHD + d4 * 4);
#pragma unroll
      for (int i = 0; i < 4; i++) {
        int d = d4 * 4 + i;
        uint32_t e0 = (((i & 2) ? vr[0].y : vr[0].x) >> ((i & 1) * 16)) & 0xffffu;
        uint32_t e1 = (((i & 2) ? vr[1].y : vr[1].x) >> ((i & 1) * 16)) & 0xffffu;
        uint32_t e2 = (((i & 2) ? vr[2].y : vr[2].x) >> ((i & 1) * 16)) & 0xffffu;
        uint32_t e3 = (((i & 2) ? vr[3].y : vr[3].x) >> ((i & 1) * 16)) & 0xffffu;
        uint2 outw = {e0 | (e1 << 16), e2 | (e3 << 16)};
        int cpr = (jg >> 1) ^ (d & 15);
        *reinterpret_cast<uint2*>(Vthi + d * 128 + cpr * 8 + (jg & 1) * 4) = outw;
      }
    }
  }
  __syncthreads();

  const int lane = tid & 63, w = tid >> 6;
  const int l16 = lane & 15, lg = lane >> 4;

  // ---- QK^T (bf16x3), wave w -> q-rows 16w..16w+15 ----
  f32x4 acc[8];
#pragma unroll
  for (int nt = 0; nt < 8; nt++) acc[nt] = {0.f, 0.f, 0.f, 0.f};

#pragma unroll
  for (int ks = 0; ks < 2; ks++) {
    int aoff = (64 + w * 16 + l16) * 68 + ks * 32 + lg * 8;
    short8 a_hi = ldsK(Khi + aoff);
    short8 a_lo = ldsK(Klo + aoff);
#pragma unroll
    for (int nt = 0; nt < 8; nt++) {
      int boff = (nt * 16 + l16) * 68 + ks * 32 + lg * 8;
      short8 b_hi = ldsK(Khi + boff);
      short8 b_lo = ldsK(Klo + boff);
      acc[nt] = __builtin_amdgcn_mfma_f32_16x16x32_bf16(a_hi, b_hi, acc[nt], 0, 0, 0);
      acc[nt] = __builtin_amdgcn_mfma_f32_16x16x32_bf16(a_lo, b_hi, acc[nt], 0, 0, 0);
      acc[nt] = __builtin_amdgcn_mfma_f32_16x16x32_bf16(a_hi, b_lo, acc[nt], 0, 0, 0);
    }
  }

  // ---- register softmax on the D-layout ----
  float invc[8]; int kpc[8];
#pragma unroll
  for (int nt = 0; nt < 8; nt++) {
    invc[nt] = invn[nt * 16 + l16] * 0.125f;
    kpc[nt] = kpos[nt * 16 + l16];
  }
  float pll[4];
#pragma unroll
  for (int r = 0; r < 4; r++) {
    int q = w * 16 + lg * 4 + r;
    int qp = kpos[64 + q];
    float mm = -3.0e38f;
#pragma unroll
    for (int nt = 0; nt < 8; nt++) {
      float s = acc[nt][r] * invc[nt];
      if (qp == kpc[nt]) s = -5e4f;
      acc[nt][r] = s;
      mm = fmaxf(mm, s);
    }
    mm = fmaxf(mm, __shfl_xor(mm, 1, 64));
    mm = fmaxf(mm, __shfl_xor(mm, 2, 64));
    mm = fmaxf(mm, __shfl_xor(mm, 4, 64));
    mm = fmaxf(mm, __shfl_xor(mm, 8, 64));
    float ll = 0.f;
#pragma unroll
    for (int nt = 0; nt < 8; nt++) {
      float p = __expf(acc[nt][r] - mm);
      acc[nt][r] = p;
      ll += p;
    }
    ll += __shfl_xor(ll, 1, 64);
    ll += __shfl_xor(ll, 2, 64);
    ll += __shfl_xor(ll, 4, 64);
    ll += __shfl_xor(ll, 8, 64);
    if (l16 == 0)
      lse_out[(size_t)bh * (NHASH * LSEQ) + h * LSEQ + qp] = mm + __logf(ll);
    pll[r] = 1.0f / ll;
  }
  __syncthreads();   // all K-plane reads done; safe to alias P32

  // ---- write P (packed hi|lo u32) ----
#pragma unroll
  for (int r = 0; r < 4; r++) {
    int q = w * 16 + lg * 4 + r;
#pragma unroll
    for (int nt = 0; nt < 8; nt++) {
      uint32_t phi, plo;
      split2(acc[nt][r], phi, plo);
      P32[q * 132 + nt * 16 + l16] = (plo << 16) | phi;
    }
  }
  // no barrier: wave reads back only its own 16 P rows

  // ---- PV: O = P.Vhi (2-term) ----
  f32x4 oacc[4];
#pragma unroll
  for (int nt = 0; nt < 4; nt++) oacc[nt] = {0.f, 0.f, 0.f, 0.f};

#pragma unroll
  for (int ks = 0; ks < 4; ks++) {
    const uint32_t* pr = P32 + (w * 16 + l16) * 132 + ks * 32 + lg * 8;
    uint4 ua = *reinterpret_cast<const uint4*>(pr);
    uint4 ub = *reinterpret_cast<const uint4*>(pr + 4);
    uint32_t u[8] = {ua.x, ua.y, ua.z, ua.w, ub.x, ub.y, ub.z, ub.w};
    union { uint32_t w4[4]; short8 s8; } ph, pl;
#pragma unroll
    for (int k2 = 0; k2 < 4; k2++) {
      ph.w4[k2] = (u[2 * k2] & 0xffffu) | (u[2 * k2 + 1] << 16);
      pl.w4[k2] = (u[2 * k2] >> 16) | (u[2 * k2 + 1] & 0xffff0000u);
    }
    const int cc = ks * 4 + lg;
#pragma unroll
    for (int nt = 0; nt < 4; nt++) {
      int voff = (nt * 16 + l16) * 128 + ((cc ^ l16) & 15) * 8;
      short8 v_hi = *reinterpret_cast<const short8*>(Vthi + voff);
      oacc[nt] = __builtin_amdgcn_mfma_f32_16x16x32_bf16(ph.s8, v_hi, oacc[nt], 0, 0, 0);
      oacc[nt] = __builtin_amdgcn_mfma_f32_16x16x32_bf16(pl.s8, v_hi, oacc[nt], 0, 0, 0);
    }
  }

  // ---- normalize + write O (bf16, unsorted) ----
  {
    uint16_t* ob = o + ((size_t)bh * (NHASH * LSEQ) + (size_t)h * LSEQ) * DHD;
#pragma unroll
    for (int r = 0; r < 4; r++) {
      int q = w * 16 + lg * 4 + r;
      int qp = kpos[64 + q];
      float s = pll[r];
#pragma unroll
      for (int nt = 0; nt < 4; nt++)
        ob[(size_t)qp * DHD + nt * 16 + l16] = (uint16_t)f2bf(oacc[nt][r] * s);
    }
  }
}

// ---------------------------------------------------------------------------
// K5: combine hash rounds -> comb bf16 hi/lo planes.  UNCHANGED.
// ---------------------------------------------------------------------------
__global__ __launch_bounds__(256) void combine_kernel(
    const uint16_t* __restrict__ o, const float* __restrict__ lse,
    uint16_t* __restrict__ comb_hi, uint16_t* __restrict__ comb_lo)
{
  int gid = blockIdx.x * 4 + (threadIdx.x >> 6);
  int lane = threadIdx.x & 63;
  int bh = gid >> 12;
  int pos = gid & 4095;
  const float* lb = &lse[(size_t)bh * (NHASH * LSEQ) + pos];
  float l0 = lb[0], l1 = lb[LSEQ], l2 = lb[2 * LSEQ], l3 = lb[3 * LSEQ];
  float m = fmaxf(fmaxf(l0, l1), fmaxf(l2, l3));
  float w0 = __expf(l0 - m), w1 = __expf(l1 - m), w2 = __expf(l2 - m), w3 = __expf(l3 - m);
  float inv = 1.0f / (w0 + w1 + w2 + w3);
  const uint16_t* ob = &o[((size_t)bh * (NHASH * LSEQ) + pos) * DHD];
  float val = (w0 * bf2f(ob[lane]) + w1 * bf2f(ob[(size_t)LSEQ * DHD + lane]) +
               w2 * bf2f(ob[(size_t)2 * LSEQ * DHD + lane]) +
               w3 * bf2f(ob[(size_t)3 * LSEQ * DHD + lane])) * inv;
  int b = bh >> 3, head = bh & 7;
  size_t idx = ((size_t)(b * LSEQ + pos)) * CDIM + head * DHD + lane;
  uint32_t hi, lo;
  split2(val, hi, lo);
  comb_hi[idx] = (uint16_t)hi;
  comb_lo[idx] = (uint16_t)lo;
}

// ---------------------------------------------------------------------------
// K5b: Wo prep — split + transpose to woT[n][k] bf16 planes.  UNCHANGED.
// ---------------------------------------------------------------------------
__global__ __launch_bounds__(256) void prep_wo_kernel(
    const float* __restrict__ Wo, uint16_t* __restrict__ th,
    uint16_t* __restrict__ tl)
{
  int idx = blockIdx.x * 256 + threadIdx.x;   // k*512 + n
  int k = idx >> 9, n = idx & 511;
  uint32_t hi, lo;
  split2(Wo[idx], hi, lo);
  th[n * 512 + k] = (uint16_t)hi;
  tl[n * 512 + k] = (uint16_t)lo;
}

// ---------------------------------------------------------------------------
// K6: output GEMM, bf16x3 MFMA.  UNCHANGED.
// ---------------------------------------------------------------------------
__global__ __launch_bounds__(256) void gemm_out_kernel(
    const uint16_t* __restrict__ Ahi_g, const uint16_t* __restrict__ Alo_g,
    const uint16_t* __restrict__ Bhi_g, const uint16_t* __restrict__ Blo_g,
    const float* __restrict__ bias, float* __restrict__ out)
{
  __shared__ __align__(16) uint16_t Ah[128 * 40];
  __shared__ __align__(16) uint16_t Al[128 * 40];
  __shared__ __align__(16) uint16_t Bh[128 * 40];
  __shared__ __align__(16) uint16_t Bl[128 * 40];
  const int tid = threadIdx.x;
  const int m0 = blockIdx.x * 128, n0 = blockIdx.y * 128;
  const int lane = tid & 63, w = tid >> 6;
  const int l16 = lane & 15, lg = lane >> 4;
  const int mq = w >> 1, nq = w & 1;
  f32x4 acc[4][4];
#pragma unroll
  for (int i = 0; i < 4; i++)
#pragma unroll
    for (int j = 0; j < 4; j++) acc[i][j] = {0.f, 0.f, 0.f, 0.f};

  const int srow = tid >> 1, sh = tid & 1;
  for (int kb = 0; kb < CDIM; kb += 32) {
    {
      const uint4* sa_h = (const uint4*)(Ahi_g + (size_t)(m0 + srow) * CDIM + kb + sh * 16);
      const uint4* sa_l = (const uint4*)(Alo_g + (size_t)(m0 + srow) * CDIM + kb + sh * 16);
      const uint4* sb_h = (const uint4*)(Bhi_g + (size_t)(n0 + srow) * CDIM + kb + sh * 16);
      const uint4* sb_l = (const uint4*)(Blo_g + (size_t)(n0 + srow) * CDIM + kb + sh * 16);
      uint4* da_h = (uint4*)(Ah + srow * 40 + sh * 16);
      uint4* da_l = (uint4*)(Al + srow * 40 + sh * 16);
      uint4* db_h = (uint4*)(Bh + srow * 40 + sh * 16);
      uint4* db_l = (uint4*)(Bl + srow * 40 + sh * 16);
      da_h[0] = sa_h[0]; da_h[1] = sa_h[1];
      da_l[0] = sa_l[0]; da_l[1] = sa_l[1];
      db_h[0] = sb_h[0]; db_h[1] = sb_h[1];
      db_l[0] = sb_l[0]; db_l[1] = sb_l[1];
    }
    __syncthreads();
    short8 fa_h[4], fa_l[4], fb_h[4], fb_l[4];
#pragma unroll
    for (int mt = 0; mt < 4; mt++) {
      int ao = (mq * 64 + mt * 16 + l16) * 40 + lg * 8;
      fa_h[mt] = *reinterpret_cast<const short8*>(Ah + ao);
      fa_l[mt] = *reinterpret_cast<const short8*>(Al + ao);
    }
#pragma unroll
    for (int nt = 0; nt < 4; nt++) {
      int bo_ = (nq * 64 + nt * 16 + l16) * 40 + lg * 8;
      fb_h[nt] = *reinterpret_cast<const short8*>(Bh + bo_);
      fb_l[nt] = *reinterpret_cast<const short8*>(Bl + bo_);
    }
#pragma unroll
    for (int mt = 0; mt < 4; mt++)
#pragma unroll
      for (int nt = 0; nt < 4; nt++) {
        acc[mt][nt] = __builtin_amdgcn_mfma_f32_16x16x32_bf16(fa_h[mt], fb_h[nt], acc[mt][nt], 0, 0, 0);
        acc[mt][nt] = __builtin_amdgcn_mfma_f32_16x16x32_bf16(fa_l[mt], fb_h[nt], acc[mt][nt], 0, 0, 0);
        acc[mt][nt] = __builtin_amdgcn_mfma_f32_16x16x32_bf16(fa_h[mt], fb_l[nt], acc[mt][nt], 0, 0, 0);
      }
    __syncthreads();
  }
#pragma unroll
  for (int nt = 0; nt < 4; nt++) {
    int n = n0 + nq * 64 + nt * 16 + l16;
    float bv = bias[n];
#pragma unroll
    for (int mt = 0; mt < 4; mt++) {
#pragma unroll
      for (int rr = 0; rr < 4; rr++) {
        int m = m0 + mq * 64 + mt * 16 + lg * 4 + rr;
        out[(size_t)m * CDIM + n] = acc[mt][nt][rr] + bv;
      }
    }
  }
}

// ---------------------------------------------------------------------------
extern "C" void kernel_launch(void* const* d_in, const int* in_sizes, int n_in,
                              void* d_out, int out_size, void* d_ws, size_t ws_size,
                              hipStream_t stream) {
  (void)in_sizes; (void)n_in; (void)out_size; (void)ws_size;
  const float* X    = (const float*)d_in[0];   // queries (4,4096,512)
  const float* Wqk  = (const float*)d_in[6];
  const float* Wv   = (const float*)d_in[7];
  const float* Wo   = (const float*)d_in[8];
  const float* bo   = (const float*)d_in[9];
  const float* rot  = (const float*)d_in[10];  // (64, 4, 32)

  // workspace layout (bytes), peak ~160 MB
  uint8_t* W = (uint8_t*)d_ws;
  float*    qk      = (float*)(W + 0);              // 33,554,432 B
  uint16_t* obuf    = (uint16_t*)(W + 33554432);    // 67,108,864 B
  uint16_t* qkhi    = (uint16_t*)(W + 100663296);   // 16,777,216 B
  uint16_t* qklo    = (uint16_t*)(W + 117440512);   // 16,777,216 B
  uint16_t* vhi     = (uint16_t*)(W + 134217728);   // 16,777,216 B
  int*      buckets = (int*)(W + 150994944);        //  2,097,152 B
  int*      st      = (int*)(W + 153092096);        //  2,097,152 B
  float*    lse     = (float*)(W + 155189248);      //  2,097,152 B
  float*    invn_g  = (float*)(W + 157286400);      //    524,288 B
  uint16_t* woT_hi  = (uint16_t*)(W + 157810688);   //    524,288 B
  uint16_t* woT_lo  = (uint16_t*)(W + 158334976);   //    524,288 B
  uint16_t* wvT0    = (uint16_t*)(W + 158859264);   //    524,288 B
  uint16_t* wvT1    = (uint16_t*)(W + 159383552);   // end 159,907,840
  // X planes alias obuf (dead until attn; gemm_v consumes them first)
  uint16_t* x0      = (uint16_t*)(W + 33554432);    // 16,777,216 B each
  uint16_t* x1      = (uint16_t*)(W + 50331648);
  uint16_t* comb_hi = (uint16_t*)(W + 0);           // alias qk (dead post-hash)
  uint16_t* comb_lo = (uint16_t*)(W + 16777216);

  hipLaunchKernelGGL(prep_x_kernel, dim3(8192), dim3(256), 0, stream,
                     X, x0, x1);
  hipLaunchKernelGGL(prep_wv_kernel, dim3(16, 16), dim3(256), 0, stream,
                     Wv, wvT0, wvT1);
  hipLaunchKernelGGL(gemm_qk_kernel, dim3(128, 8), dim3(256), 0, stream,
                     X, Wqk, qk, qkhi, qklo, invn_g);
  hipLaunchKernelGGL(gemm_v_mfma_kernel, dim3(128, 4), dim3(512), 0, stream,
                     x0, x1, wvT0, wvT1, vhi);
  hipLaunchKernelGGL(hash_kernel, dim3(16, 32), dim3(256), 0, stream,
                     qk, rot, buckets);
  hipLaunchKernelGGL(sort_kernel, dim3(4, 32), dim3(256), 0, stream,
                     buckets, st);
  hipLaunchKernelGGL(prep_wo_kernel, dim3(1024), dim3(256), 0, stream,
                     Wo, woT_hi, woT_lo);
  hipLaunchKernelGGL(attn_kernel, dim3(256, 32), dim3(256), 0, stream,
                     qkhi, qklo, vhi, invn_g, st, obuf, lse);
  hipLaunchKernelGGL(combine_kernel, dim3(32768), dim3(256), 0, stream,
                     obuf, lse, comb_hi, comb_lo);
  hipLaunchKernelGGL(gemm_out_kernel, dim3(128, 4), dim3(256), 0, stream,
                     comb_hi, comb_lo, woT_hi, woT_lo, bo, (float*)d_out);
}

// Round 7
// 439.584 us; speedup vs baseline: 2.1592x; 1.0467x over previous
//
#include <hip/hip_runtime.h>
#include <hip/hip_bf16.h>
#include <cstdint>
#include <cstddef>

// Problem constants (fixed by setup_inputs)
#define LSEQ   4096
#define DHD    64
#define NHASH  4
#define CDIM   512
#define NBH    32        // B*HEADS
#define MROWS  16384     // B*LSEQ
#define NCHUNK 256       // NHASH*LSEQ/64

typedef __attribute__((ext_vector_type(8))) short short8;
typedef __attribute__((ext_vector_type(4))) float f32x4;
typedef __attribute__((ext_vector_type(2))) float f32x2;

__device__ inline uint32_t f2bf(float f) {
  uint32_t u = __float_as_uint(f);
  return (u + 0x7FFFu + ((u >> 16) & 1u)) >> 16;
}
__device__ inline float bf2f(uint32_t h) { return __uint_as_float(h << 16); }
__device__ inline void split2(float f, uint32_t& hi, uint32_t& lo) {
  hi = f2bf(f);
  lo = f2bf(f - bf2f(hi));
}
// HW packed f32->bf16 (RNE, same bits as f2bf for normal values):
// low16 = bf16(a), high16 = bf16(b)
__device__ inline uint32_t cvtpk_bf16(float a, float b) {
  uint32_t r;
  asm("v_cvt_pk_bf16_f32 %0, %1, %2" : "=v"(r) : "v"(a), "v"(b));
  return r;
}
__device__ inline short8 ldsK(const uint16_t* p) {   // two b64 reads -> short8
  union { uint2 u[2]; short8 s; } t;
  t.u[0] = *reinterpret_cast<const uint2*>(p);
  t.u[1] = *reinterpret_cast<const uint2*>(p + 4);
  return t.s;
}

// ---------------------------------------------------------------------------
// K0: fused prep.  blocks [0,8192): X->2 bf16 planes; [8192,9216): Wo split+
// transpose; [9216,9472): Wv split+transpose.
// ---------------------------------------------------------------------------
__global__ __launch_bounds__(256) void prep_kernel(
    const float* __restrict__ X, const float* __restrict__ Wv,
    const float* __restrict__ Wo,
    uint16_t* __restrict__ X0, uint16_t* __restrict__ X1,
    uint16_t* __restrict__ wvT0, uint16_t* __restrict__ wvT1,
    uint16_t* __restrict__ woT_hi, uint16_t* __restrict__ woT_lo)
{
  __shared__ float Ts[32][33];
  const int bid = blockIdx.x, tid = threadIdx.x;
  if (bid < 8192) {
    size_t i = ((size_t)bid * 256 + tid) * 4;
    float4 v = *reinterpret_cast<const float4*>(X + i);
    uint32_t h01 = cvtpk_bf16(v.x, v.y);
    uint32_t h23 = cvtpk_bf16(v.z, v.w);
    float r0 = v.x - __uint_as_float(h01 << 16);
    float r1 = v.y - __uint_as_float(h01 & 0xffff0000u);
    float r2 = v.z - __uint_as_float(h23 << 16);
    float r3 = v.w - __uint_as_float(h23 & 0xffff0000u);
    uint2 hw = {h01, h23};
    uint2 lw = {cvtpk_bf16(r0, r1), cvtpk_bf16(r2, r3)};
    *reinterpret_cast<uint2*>(X0 + i) = hw;
    *reinterpret_cast<uint2*>(X1 + i) = lw;
  } else if (bid < 9216) {
    int idx = (bid - 8192) * 256 + tid;   // k*512 + n
    int k = idx >> 9, n = idx & 511;
    uint32_t hi, lo;
    split2(Wo[idx], hi, lo);
    woT_hi[n * 512 + k] = (uint16_t)hi;
    woT_lo[n * 512 + k] = (uint16_t)lo;
  } else {
    int wb = bid - 9216;                  // 0..255
    const int k0 = (wb >> 4) * 32, n0 = (wb & 15) * 32;
#pragma unroll
    for (int i = 0; i < 4; i++) {
      int flat = i * 256 + tid;
      int r = flat >> 5, c = flat & 31;
      Ts[r][c] = Wv[(size_t)(k0 + r) * 512 + n0 + c];
    }
    __syncthreads();
#pragma unroll
    for (int i = 0; i < 4; i++) {
      int flat = i * 256 + tid;
      int nr = flat >> 5, kc = flat & 31;
      uint32_t h, l;
      split2(Ts[kc][nr], h, l);
      size_t idx = (size_t)(n0 + nr) * 512 + k0 + kc;
      wvT0[idx] = (uint16_t)h;
      wvT1[idx] = (uint16_t)l;
    }
  }
}

// ---------------------------------------------------------------------------
// K1a: qk projection GEMM — FROZEN MATH.  Per output element the chain is
// the identical k-ascending `acc += a*b` fmuladd sequence that passed
// r1-r4 (scalar) and r6 (f32x2) — bitwise-preserved buckets.  Retiled to
// 128x128 / thread 8x8 for 2x arithmetic intensity.  grid (128,4), 256 thr.
// Epilogue: qk f32 + bf16 hi/lo planes (cvt_pk, same RNE bits) + invn.
// ---------------------------------------------------------------------------
__global__ __launch_bounds__(256) void gemm_qk_kernel(
    const float* __restrict__ X, const float* __restrict__ Wqk,
    float* __restrict__ qk, uint16_t* __restrict__ qkhi,
    uint16_t* __restrict__ qklo, float* __restrict__ invn_g)
{
  const int m0 = blockIdx.x * 128;
  const int n0 = blockIdx.y * 128;
  __shared__ float As[32][132];   // [k][m]
  __shared__ float Bs[32][132];   // [k][n]
  const int tid = threadIdx.x;
  const int r = tid >> 4, c = tid & 15;   // rows 8r.., cols 8c..
  f32x2 acc2[8][4];
#pragma unroll
  for (int i = 0; i < 8; i++)
#pragma unroll
    for (int j = 0; j < 4; j++) acc2[i][j] = {0.f, 0.f};

  const int arow = tid >> 3;   // 0..31
  const int ac4  = tid & 7;
  const int brow = tid >> 5;   // 0..7
  const int bc4  = tid & 31;

  for (int kb = 0; kb < CDIM; kb += 32) {
#pragma unroll
    for (int rr = 0; rr < 4; rr++) {
      int m = arow + rr * 32;
      float4 av = *reinterpret_cast<const float4*>(&X[(size_t)(m0 + m) * CDIM + kb + ac4 * 4]);
      As[ac4 * 4 + 0][m] = av.x;
      As[ac4 * 4 + 1][m] = av.y;
      As[ac4 * 4 + 2][m] = av.z;
      As[ac4 * 4 + 3][m] = av.w;
    }
#pragma unroll
    for (int rr = 0; rr < 4; rr++) {
      int kk = brow + rr * 8;
      *reinterpret_cast<float4*>(&Bs[kk][bc4 * 4]) =
          *reinterpret_cast<const float4*>(&Wqk[(size_t)(kb + kk) * CDIM + n0 + bc4 * 4]);
    }
    __syncthreads();
#pragma unroll
    for (int k = 0; k < 32; k++) {
      float4 a0 = *reinterpret_cast<const float4*>(&As[k][r * 8]);
      float4 a1 = *reinterpret_cast<const float4*>(&As[k][r * 8 + 4]);
      float4 b0 = *reinterpret_cast<const float4*>(&Bs[k][c * 8]);
      float4 b1 = *reinterpret_cast<const float4*>(&Bs[k][c * 8 + 4]);
      float am[8] = {a0.x, a0.y, a0.z, a0.w, a1.x, a1.y, a1.z, a1.w};
      f32x2 bp[4] = {{b0.x, b0.y}, {b0.z, b0.w}, {b1.x, b1.y}, {b1.z, b1.w}};
#pragma unroll
      for (int i = 0; i < 8; i++) {
        f32x2 av = {am[i], am[i]};
#pragma unroll
        for (int jp = 0; jp < 4; jp++)
          acc2[i][jp] += av * bp[jp];   // fmuladd per component, k-ascending
      }
    }
    __syncthreads();
  }
  // epilogue: thread covers rows m0+r*8+ii, cols n0 + c*8 + j (one head each)
  const int head = (n0 >> 6) + (c >> 3);
#pragma unroll
  for (int ii = 0; ii < 8; ii++) {
    int m = m0 + r * 8 + ii;
    int b = m >> 12, t = m & 4095;
    size_t base = ((size_t)(b * 8 + head) * LSEQ + t) * DHD + (c & 7) * 8;
    float vals[8] = {acc2[ii][0][0], acc2[ii][0][1], acc2[ii][1][0], acc2[ii][1][1],
                     acc2[ii][2][0], acc2[ii][2][1], acc2[ii][3][0], acc2[ii][3][1]};
    *reinterpret_cast<float4*>(&qk[base]) = {vals[0], vals[1], vals[2], vals[3]};
    *reinterpret_cast<float4*>(&qk[base + 4]) = {vals[4], vals[5], vals[6], vals[7]};
    uint32_t hw[4], lw[4];
#pragma unroll
    for (int p = 0; p < 4; p++) {
      float x = vals[2 * p], y = vals[2 * p + 1];
      uint32_t h = cvtpk_bf16(x, y);
      float rx = x - __uint_as_float(h << 16);
      float ry = y - __uint_as_float(h & 0xffff0000u);
      hw[p] = h;
      lw[p] = cvtpk_bf16(rx, ry);
    }
    *reinterpret_cast<uint2*>(&qkhi[base]) = {hw[0], hw[1]};
    *reinterpret_cast<uint2*>(&qkhi[base + 4]) = {hw[2], hw[3]};
    *reinterpret_cast<uint2*>(&qklo[base]) = {lw[0], lw[1]};
    *reinterpret_cast<uint2*>(&qklo[base + 4]) = {lw[2], lw[3]};
    float ss = 0.f;
#pragma unroll
    for (int j = 0; j < 8; j++) ss += vals[j] * vals[j];
    ss += __shfl_xor(ss, 1, 64);
    ss += __shfl_xor(ss, 2, 64);
    ss += __shfl_xor(ss, 4, 64);
    if ((c & 7) == 0)
      invn_g[(size_t)(b * 8 + head) * LSEQ + t] = 1.0f / fmaxf(sqrtf(ss), 1e-12f);
  }
}

// ---------------------------------------------------------------------------
// K1b: v projection via bf16-split MFMA (3-term).  UNCHANGED except cvt_pk
// in epilogue.  grid (128, 4), block 512.
// ---------------------------------------------------------------------------
__global__ __launch_bounds__(512) void gemm_v_mfma_kernel(
    const uint16_t* __restrict__ X0g, const uint16_t* __restrict__ X1g,
    const uint16_t* __restrict__ Wv0, const uint16_t* __restrict__ Wv1,
    uint16_t* __restrict__ vhi)
{
  __shared__ __align__(16) uint16_t Xs[2 * 128 * 40];
  __shared__ __align__(16) uint16_t Ws[2 * 128 * 40];
  const int tid = threadIdx.x;
  const int m0 = blockIdx.x * 128;
  const int n0 = blockIdx.y * 128;
  const int lane = tid & 63, w = tid >> 6;
  const int l16 = lane & 15, lg = lane >> 4;

  f32x4 acc[8];
#pragma unroll
  for (int nt = 0; nt < 8; nt++) acc[nt] = {0.f, 0.f, 0.f, 0.f};

  const int srow = tid >> 3;
  const int sch = (tid & 7) * 4;

  for (int kb = 0; kb < CDIM; kb += 32) {
#pragma unroll
    for (int i = 0; i < 4; i++) {
      int p = i >> 1;
      int row = (i & 1) * 64 + srow;
      const uint16_t* xg = (p == 0) ? X0g : X1g;
      const uint16_t* wg = (p == 0) ? Wv0 : Wv1;
      *reinterpret_cast<uint2*>(Xs + p * 5120 + row * 40 + sch) =
          *reinterpret_cast<const uint2*>(xg + (size_t)(m0 + row) * 512 + kb + sch);
      *reinterpret_cast<uint2*>(Ws + p * 5120 + row * 40 + sch) =
          *reinterpret_cast<const uint2*>(wg + (size_t)(n0 + row) * 512 + kb + sch);
    }
    __syncthreads();

    const int abase = (w * 16 + l16) * 40 + lg * 8;
    short8 a0 = *reinterpret_cast<const short8*>(Xs + abase);
    short8 a1 = *reinterpret_cast<const short8*>(Xs + 5120 + abase);
#pragma unroll
    for (int nt = 0; nt < 8; nt++) {
      int bbase = (nt * 16 + l16) * 40 + lg * 8;
      short8 b0 = *reinterpret_cast<const short8*>(Ws + bbase);
      short8 b1 = *reinterpret_cast<const short8*>(Ws + 5120 + bbase);
      acc[nt] = __builtin_amdgcn_mfma_f32_16x16x32_bf16(a0, b0, acc[nt], 0, 0, 0);
      acc[nt] = __builtin_amdgcn_mfma_f32_16x16x32_bf16(a1, b0, acc[nt], 0, 0, 0);
      acc[nt] = __builtin_amdgcn_mfma_f32_16x16x32_bf16(a0, b1, acc[nt], 0, 0, 0);
    }
    __syncthreads();
  }

#pragma unroll
  for (int rr = 0; rr < 4; rr++) {
    int mg = m0 + w * 16 + lg * 4 + rr;
    int b = mg >> 12, t = mg & 4095;
#pragma unroll
    for (int nt = 0; nt < 8; nt++) {
      int head = (n0 >> 6) + (nt >> 2);
      size_t base = ((size_t)(b * 8 + head) * LSEQ + t) * DHD + (nt & 3) * 16 + l16;
      vhi[base] = (uint16_t)cvtpk_bf16(acc[nt][rr], acc[nt][rr]);
    }
  }
}

// ---------------------------------------------------------------------------
// K2: LSH hashing.  UNCHANGED (bucket determinism; reads frozen f32 qk).
// ---------------------------------------------------------------------------
__global__ __launch_bounds__(256) void hash_kernel(
    const float* __restrict__ qk, const float* __restrict__ rot,
    int* __restrict__ buckets)
{
  __shared__ float rotT[128][68];   // [h*32+i][f]
  const int tid = threadIdx.x;
  for (int idx = tid; idx < 64 * 128; idx += 256) {
    int f = idx >> 7, hi = idx & 127;
    rotT[hi][f] = rot[idx];
  }
  __syncthreads();
  const int bh = blockIdx.y;
  const int t = blockIdx.x * 256 + tid;
  float4 row4[16];
  const float* src = &qk[((size_t)bh * LSEQ + t) * DHD];
#pragma unroll
  for (int i = 0; i < 16; i++) row4[i] = reinterpret_cast<const float4*>(src)[i];

  int* bout = &buckets[(size_t)bh * NHASH * LSEQ];
  for (int h = 0; h < NHASH; h++) {
    float rc[32];
    float best = -3.0e38f;
    int bidx = 0;
#pragma unroll 4
    for (int i = 0; i < 32; i++) {
      const float* rr = &rotT[h * 32 + i][0];
      float a = 0.f;
#pragma unroll
      for (int f4 = 0; f4 < 16; f4++) {
        float4 rv = reinterpret_cast<const float4*>(rr)[f4];
        a += row4[f4].x * rv.x + row4[f4].y * rv.y + row4[f4].z * rv.z + row4[f4].w * rv.w;
      }
      rc[i] = a;
      if (a > best) { best = a; bidx = i; }
    }
#pragma unroll
    for (int i = 0; i < 32; i++) {
      float nv = -rc[i];
      if (nv > best) { best = nv; bidx = 32 + i; }
    }
    bout[h * LSEQ + t] = bidx;
  }
}

// ---------------------------------------------------------------------------
// K3: stable counting sort per (bh, h).  UNCHANGED.
// ---------------------------------------------------------------------------
__global__ __launch_bounds__(256) void sort_kernel(
    const int* __restrict__ buckets, int* __restrict__ st)
{
  __shared__ int hist[64][64];
  const int h = blockIdx.x, bh = blockIdx.y;
  const int tid = threadIdx.x;
  const int* bk = &buckets[((size_t)bh * NHASH + h) * LSEQ];

  for (int i = tid; i < 64 * 64; i += 256) (&hist[0][0])[i] = 0;
  __syncthreads();
  for (int t = tid; t < LSEQ; t += 256) {
    int b = bk[t];
    atomicAdd(&hist[t >> 6][b], 1);
  }
  __syncthreads();
  if (tid < 64) {
    int tot = 0;
    for (int s = 0; s < 64; s++) tot += hist[s][tid];
    int vsc = tot;
    for (int off = 1; off < 64; off <<= 1) {
      int nv = __shfl_up(vsc, off, 64);
      if (tid >= off) vsc += nv;
    }
    int run = h * LSEQ + (vsc - tot);
    for (int s = 0; s < 64; s++) {
      int tmp = hist[s][tid];
      hist[s][tid] = run;
      run += tmp;
    }
  }
  __syncthreads();
  const int wave = tid >> 6, lane = tid & 63;
  for (int si = 0; si < 16; si++) {
    int seg = wave * 16 + si;
    int pos = seg * 64 + lane;
    int b = bk[pos];
    int rank = 0;
    for (int k = 0; k < 64; k++) {
      int bb = __shfl(b, k, 64);
      rank += (bb == b && k < lane) ? 1 : 0;
    }
    int dest = hist[seg][b] + rank;
    st[(size_t)bh * (NHASH * LSEQ) + dest] = pos;
  }
}

// ---------------------------------------------------------------------------
// K4: chunked attention.  Changes vs r6: XCD-aware block swizzle (each XCD
// owns 4 bh's contiguous chunks -> gather pool ~L2-resident) and cvt_pk for
// the P pack / O store (same RNE bits, ~10x fewer VALU ops per element).
// ---------------------------------------------------------------------------
__global__ __launch_bounds__(256) void attn_kernel(
    const uint16_t* __restrict__ qkhi, const uint16_t* __restrict__ qklo,
    const uint16_t* __restrict__ vhi, const float* __restrict__ invn_g,
    const int* __restrict__ st, uint16_t* __restrict__ o,
    float* __restrict__ lse_out)
{
  __shared__ __align__(16) uint8_t smem[53248];
  uint16_t* Khi  = (uint16_t*)smem;                  // [128][68] = 17408 B
  uint16_t* Klo  = Khi + 128 * 68;                   // +17408 B
  uint16_t* Vthi = (uint16_t*)(smem + 34816);        // [64][128] = 16384 B
  float*    invn = (float*)(smem + 52224);           // 128 f
  int*      kpos = (int*)(smem + 52736);             // 128 i
  uint32_t* P32  = (uint32_t*)smem;                  // [64][132] u32, alias K

  // XCD-aware swizzle: lin -> (xcd, idx); each XCD gets 4 bh x 256 chunks
  const int lin = blockIdx.y * 256 + blockIdx.x;
  const int xcd = lin & 7, sidx = lin >> 3;
  const int bh = (xcd << 2) | (sidx >> 8);
  const int cchunk = sidx & 255;

  const int tid = threadIdx.x;
  const int prev = (cchunk + NCHUNK - 1) & (NCHUNK - 1);
  const int* stb = &st[(size_t)bh * (NHASH * LSEQ)];
  const int h = cchunk >> 6;

  if (tid < 128) {
    int kp = (tid < 64) ? stb[prev * 64 + tid] : stb[cchunk * 64 + (tid - 64)];
    kpos[tid] = kp;
    invn[tid] = invn_g[(size_t)bh * LSEQ + kp];
  }
  __syncthreads();

  // ---- stage K planes (pure copies) ----
  {
    const int d4 = tid & 15, rbase = tid >> 4;
    const uint16_t* qhb = qkhi + (size_t)bh * LSEQ * DHD;
    const uint16_t* qlb = qklo + (size_t)bh * LSEQ * DHD;
#pragma unroll
    for (int it = 0; it < 8; it++) {
      int row = rbase + it * 16;
      size_t src = (size_t)kpos[row] * DHD + d4 * 4;
      *reinterpret_cast<uint2*>(Khi + row * 68 + d4 * 4) =
          *reinterpret_cast<const uint2*>(qhb + src);
      *reinterpret_cast<uint2*>(Klo + row * 68 + d4 * 4) =
          *reinterpret_cast<const uint2*>(qlb + src);
    }
  }
  // ---- stage V transposed (u16 4x4 transpose), swizzled ----
  {
    const int d4 = tid & 15, jg0 = tid >> 4;
    const uint16_t* vb = vhi + (size_t)bh * LSEQ * DHD;
#pragma unroll
    for (int half = 0; half < 2; half++) {
      int jg = jg0 + half * 16;   // 0..31, j = 4*jg..4*jg+3
      uint2 vr[4];
#pragma unroll
      for (int s = 0; s < 4; s++)
        vr[s] = *reinterpret_cast<const uint2*>(vb + (size_t)kpos[jg * 4 + s] * DHD + d4 * 4);
#pragma unroll
      for (int i = 0; i < 4; i++) {
        int d = d4 * 4 + i;
        uint32_t e0 = (((i & 2) ? vr[0].y : vr[0].x) >> ((i & 1) * 16)) & 0xffffu;
        uint32_t e1 = (((i & 2) ? vr[1].y : vr[1].x) >> ((i & 1) * 16)) & 0xffffu;
        uint32_t e2 = (((i & 2) ? vr[2].y : vr[2].x) >> ((i & 1) * 16)) & 0xffffu;
        uint32_t e3 = (((i & 2) ? vr[3].y : vr[3].x) >> ((i & 1) * 16)) & 0xffffu;
        uint2 outw = {e0 | (e1 << 16), e2 | (e3 << 16)};
        int cpr = (jg >> 1) ^ (d & 15);
        *reinterpret_cast<uint2*>(Vthi + d * 128 + cpr * 8 + (jg & 1) * 4) = outw;
      }
    }
  }
  __syncthreads();

  const int lane = tid & 63, w = tid >> 6;
  const int l16 = lane & 15, lg = lane >> 4;

  // ---- QK^T (bf16x3), wave w -> q-rows 16w..16w+15 ----
  f32x4 acc[8];
#pragma unroll
  for (int nt = 0; nt < 8; nt++) acc[nt] = {0.f, 0.f, 0.f, 0.f};

#pragma unroll
  for (int ks = 0; ks < 2; ks++) {
    int aoff = (64 + w * 16 + l16) * 68 + ks * 32 + lg * 8;
    short8 a_hi = ldsK(Khi + aoff);
    short8 a_lo = ldsK(Klo + aoff);
#pragma unroll
    for (int nt = 0; nt < 8; nt++) {
      int boff = (nt * 16 + l16) * 68 + ks * 32 + lg * 8;
      short8 b_hi = ldsK(Khi + boff);
      short8 b_lo = ldsK(Klo + boff);
      acc[nt] = __builtin_amdgcn_mfma_f32_16x16x32_bf16(a_hi, b_hi, acc[nt], 0, 0, 0);
      acc[nt] = __builtin_amdgcn_mfma_f32_16x16x32_bf16(a_lo, b_hi, acc[nt], 0, 0, 0);
      acc[nt] = __builtin_amdgcn_mfma_f32_16x16x32_bf16(a_hi, b_lo, acc[nt], 0, 0, 0);
    }
  }

  // ---- register softmax on the D-layout ----
  float invc[8]; int kpc[8];
#pragma unroll
  for (int nt = 0; nt < 8; nt++) {
    invc[nt] = invn[nt * 16 + l16] * 0.125f;
    kpc[nt] = kpos[nt * 16 + l16];
  }
  float pll[4];
#pragma unroll
  for (int r = 0; r < 4; r++) {
    int q = w * 16 + lg * 4 + r;
    int qp = kpos[64 + q];
    float mm = -3.0e38f;
#pragma unroll
    for (int nt = 0; nt < 8; nt++) {
      float s = acc[nt][r] * invc[nt];
      if (qp == kpc[nt]) s = -5e4f;
      acc[nt][r] = s;
      mm = fmaxf(mm, s);
    }
    mm = fmaxf(mm, __shfl_xor(mm, 1, 64));
    mm = fmaxf(mm, __shfl_xor(mm, 2, 64));
    mm = fmaxf(mm, __shfl_xor(mm, 4, 64));
    mm = fmaxf(mm, __shfl_xor(mm, 8, 64));
    float ll = 0.f;
#pragma unroll
    for (int nt = 0; nt < 8; nt++) {
      float p = __expf(acc[nt][r] - mm);
      acc[nt][r] = p;
      ll += p;
    }
    ll += __shfl_xor(ll, 1, 64);
    ll += __shfl_xor(ll, 2, 64);
    ll += __shfl_xor(ll, 4, 64);
    ll += __shfl_xor(ll, 8, 64);
    if (l16 == 0)
      lse_out[(size_t)bh * (NHASH * LSEQ) + h * LSEQ + qp] = mm + __logf(ll);
    pll[r] = 1.0f / ll;
  }
  __syncthreads();   // all K-plane reads done; safe to alias P32

  // ---- write P (packed hi|lo u32, via cvt_pk) ----
#pragma unroll
  for (int r = 0; r < 4; r++) {
    int q = w * 16 + lg * 4 + r;
#pragma unroll
    for (int nt = 0; nt < 8; nt++) {
      float p = acc[nt][r];
      uint32_t t1 = cvtpk_bf16(p, p);
      float res = p - __uint_as_float(t1 << 16);
      P32[q * 132 + nt * 16 + l16] = cvtpk_bf16(p, res);   // low=phi, high=plo
    }
  }
  // no barrier: wave reads back only its own 16 P rows

  // ---- PV: O = P.Vhi (2-term) ----
  f32x4 oacc[4];
#pragma unroll
  for (int nt = 0; nt < 4; nt++) oacc[nt] = {0.f, 0.f, 0.f, 0.f};

#pragma unroll
  for (int ks = 0; ks < 4; ks++) {
    const uint32_t* pr = P32 + (w * 16 + l16) * 132 + ks * 32 + lg * 8;
    uint4 ua = *reinterpret_cast<const uint4*>(pr);
    uint4 ub = *reinterpret_cast<const uint4*>(pr + 4);
    uint32_t u[8] = {ua.x, ua.y, ua.z, ua.w, ub.x, ub.y, ub.z, ub.w};
    union { uint32_t w4[4]; short8 s8; } ph, pl;
#pragma unroll
    for (int k2 = 0; k2 < 4; k2++) {
      ph.w4[k2] = (u[2 * k2] & 0xffffu) | (u[2 * k2 + 1] << 16);
      pl.w4[k2] = (u[2 * k2] >> 16) | (u[2 * k2 + 1] & 0xffff0000u);
    }
    const int cc = ks * 4 + lg;
#pragma unroll
    for (int nt = 0; nt < 4; nt++) {
      int voff = (nt * 16 + l16) * 128 + ((cc ^ l16) & 15) * 8;
      short8 v_hi = *reinterpret_cast<const short8*>(Vthi + voff);
      oacc[nt] = __builtin_amdgcn_mfma_f32_16x16x32_bf16(ph.s8, v_hi, oacc[nt], 0, 0, 0);
      oacc[nt] = __builtin_amdgcn_mfma_f32_16x16x32_bf16(pl.s8, v_hi, oacc[nt], 0, 0, 0);
    }
  }

  // ---- normalize + write O (bf16, unsorted) ----
  {
    uint16_t* ob = o + ((size_t)bh * (NHASH * LSEQ) + (size_t)h * LSEQ) * DHD;
#pragma unroll
    for (int r = 0; r < 4; r++) {
      int q = w * 16 + lg * 4 + r;
      int qp = kpos[64 + q];
      float s = pll[r];
#pragma unroll
      for (int nt = 0; nt < 4; nt++) {
        float v = oacc[nt][r] * s;
        ob[(size_t)qp * DHD + nt * 16 + l16] = (uint16_t)cvtpk_bf16(v, v);
      }
    }
  }
}

// ---------------------------------------------------------------------------
// K5: combine hash rounds -> comb bf16 hi/lo planes (cvt_pk).
// ---------------------------------------------------------------------------
__global__ __launch_bounds__(256) void combine_kernel(
    const uint16_t* __restrict__ o, const float* __restrict__ lse,
    uint16_t* __restrict__ comb_hi, uint16_t* __restrict__ comb_lo)
{
  int gid = blockIdx.x * 4 + (threadIdx.x >> 6);
  int lane = threadIdx.x & 63;
  int bh = gid >> 12;
  int pos = gid & 4095;
  const float* lb = &lse[(size_t)bh * (NHASH * LSEQ) + pos];
  float l0 = lb[0], l1 = lb[LSEQ], l2 = lb[2 * LSEQ], l3 = lb[3 * LSEQ];
  float m = fmaxf(fmaxf(l0, l1), fmaxf(l2, l3));
  float w0 = __expf(l0 - m), w1 = __expf(l1 - m), w2 = __expf(l2 - m), w3 = __expf(l3 - m);
  float inv = 1.0f / (w0 + w1 + w2 + w3);
  const uint16_t* ob = &o[((size_t)bh * (NHASH * LSEQ) + pos) * DHD];
  float val = (w0 * bf2f(ob[lane]) + w1 * bf2f(ob[(size_t)LSEQ * DHD + lane]) +
               w2 * bf2f(ob[(size_t)2 * LSEQ * DHD + lane]) +
               w3 * bf2f(ob[(size_t)3 * LSEQ * DHD + lane])) * inv;
  int b = bh >> 3, head = bh & 7;
  size_t idx = ((size_t)(b * LSEQ + pos)) * CDIM + head * DHD + lane;
  uint32_t hw = cvtpk_bf16(val, val);
  float res = val - __uint_as_float(hw << 16);
  comb_hi[idx] = (uint16_t)hw;
  comb_lo[idx] = (uint16_t)cvtpk_bf16(res, res);
}

// ---------------------------------------------------------------------------
// K6: output GEMM, bf16x3 MFMA.  UNCHANGED.
// ---------------------------------------------------------------------------
__global__ __launch_bounds__(256) void gemm_out_kernel(
    const uint16_t* __restrict__ Ahi_g, const uint16_t* __restrict__ Alo_g,
    const uint16_t* __restrict__ Bhi_g, const uint16_t* __restrict__ Blo_g,
    const float* __restrict__ bias, float* __restrict__ out)
{
  __shared__ __align__(16) uint16_t Ah[128 * 40];
  __shared__ __align__(16) uint16_t Al[128 * 40];
  __shared__ __align__(16) uint16_t Bh[128 * 40];
  __shared__ __align__(16) uint16_t Bl[128 * 40];
  const int tid = threadIdx.x;
  const int m0 = blockIdx.x * 128, n0 = blockIdx.y * 128;
  const int lane = tid & 63, w = tid >> 6;
  const int l16 = lane & 15, lg = lane >> 4;
  const int mq = w >> 1, nq = w & 1;
  f32x4 acc[4][4];
#pragma unroll
  for (int i = 0; i < 4; i++)
#pragma unroll
    for (int j = 0; j < 4; j++) acc[i][j] = {0.f, 0.f, 0.f, 0.f};

  const int srow = tid >> 1, sh = tid & 1;
  for (int kb = 0; kb < CDIM; kb += 32) {
    {
      const uint4* sa_h = (const uint4*)(Ahi_g + (size_t)(m0 + srow) * CDIM + kb + sh * 16);
      const uint4* sa_l = (const uint4*)(Alo_g + (size_t)(m0 + srow) * CDIM + kb + sh * 16);
      const uint4* sb_h = (const uint4*)(Bhi_g + (size_t)(n0 + srow) * CDIM + kb + sh * 16);
      const uint4* sb_l = (const uint4*)(Blo_g + (size_t)(n0 + srow) * CDIM + kb + sh * 16);
      uint4* da_h = (uint4*)(Ah + srow * 40 + sh * 16);
      uint4* da_l = (uint4*)(Al + srow * 40 + sh * 16);
      uint4* db_h = (uint4*)(Bh + srow * 40 + sh * 16);
      uint4* db_l = (uint4*)(Bl + srow * 40 + sh * 16);
      da_h[0] = sa_h[0]; da_h[1] = sa_h[1];
      da_l[0] = sa_l[0]; da_l[1] = sa_l[1];
      db_h[0] = sb_h[0]; db_h[1] = sb_h[1];
      db_l[0] = sb_l[0]; db_l[1] = sb_l[1];
    }
    __syncthreads();
    short8 fa_h[4], fa_l[4], fb_h[4], fb_l[4];
#pragma unroll
    for (int mt = 0; mt < 4; mt++) {
      int ao = (mq * 64 + mt * 16 + l16) * 40 + lg * 8;
      fa_h[mt] = *reinterpret_cast<const short8*>(Ah + ao);
      fa_l[mt] = *reinterpret_cast<const short8*>(Al + ao);
    }
#pragma unroll
    for (int nt = 0; nt < 4; nt++) {
      int bo_ = (nq * 64 + nt * 16 + l16) * 40 + lg * 8;
      fb_h[nt] = *reinterpret_cast<const short8*>(Bh + bo_);
      fb_l[nt] = *reinterpret_cast<const short8*>(Bl + bo_);
    }
#pragma unroll
    for (int mt = 0; mt < 4; mt++)
#pragma unroll
      for (int nt = 0; nt < 4; nt++) {
        acc[mt][nt] = __builtin_amdgcn_mfma_f32_16x16x32_bf16(fa_h[mt], fb_h[nt], acc[mt][nt], 0, 0, 0);
        acc[mt][nt] = __builtin_amdgcn_mfma_f32_16x16x32_bf16(fa_l[mt], fb_h[nt], acc[mt][nt], 0, 0, 0);
        acc[mt][nt] = __builtin_amdgcn_mfma_f32_16x16x32_bf16(fa_h[mt], fb_l[nt], acc[mt][nt], 0, 0, 0);
      }
    __syncthreads();
  }
#pragma unroll
  for (int nt = 0; nt < 4; nt++) {
    int n = n0 + nq * 64 + nt * 16 + l16;
    float bv = bias[n];
#pragma unroll
    for (int mt = 0; mt < 4; mt++) {
#pragma unroll
      for (int rr = 0; rr < 4; rr++) {
        int m = m0 + mq * 64 + mt * 16 + lg * 4 + rr;
        out[(size_t)m * CDIM + n] = acc[mt][nt][rr] + bv;
      }
    }
  }
}

// ---------------------------------------------------------------------------
extern "C" void kernel_launch(void* const* d_in, const int* in_sizes, int n_in,
                              void* d_out, int out_size, void* d_ws, size_t ws_size,
                              hipStream_t stream) {
  (void)in_sizes; (void)n_in; (void)out_size; (void)ws_size;
  const float* X    = (const float*)d_in[0];   // queries (4,4096,512)
  const float* Wqk  = (const float*)d_in[6];
  const float* Wv   = (const float*)d_in[7];
  const float* Wo   = (const float*)d_in[8];
  const float* bo   = (const float*)d_in[9];
  const float* rot  = (const float*)d_in[10];  // (64, 4, 32)

  // workspace layout (bytes), peak ~160 MB
  uint8_t* W = (uint8_t*)d_ws;
  float*    qk      = (float*)(W + 0);              // 33,554,432 B
  uint16_t* obuf    = (uint16_t*)(W + 33554432);    // 67,108,864 B
  uint16_t* qkhi    = (uint16_t*)(W + 100663296);   // 16,777,216 B
  uint16_t* qklo    = (uint16_t*)(W + 117440512);   // 16,777,216 B
  uint16_t* vhi     = (uint16_t*)(W + 134217728);   // 16,777,216 B
  int*      buckets = (int*)(W + 150994944);        //  2,097,152 B
  int*      st      = (int*)(W + 153092096);        //  2,097,152 B
  float*    lse     = (float*)(W + 155189248);      //  2,097,152 B
  float*    invn_g  = (float*)(W + 157286400);      //    524,288 B
  uint16_t* woT_hi  = (uint16_t*)(W + 157810688);   //    524,288 B
  uint16_t* woT_lo  = (uint16_t*)(W + 158334976);   //    524,288 B
  uint16_t* wvT0    = (uint16_t*)(W + 158859264);   //    524,288 B
  uint16_t* wvT1    = (uint16_t*)(W + 159383552);   // end 159,907,840
  // X planes alias obuf (dead until attn; gemm_v consumes them first)
  uint16_t* x0      = (uint16_t*)(W + 33554432);    // 16,777,216 B each
  uint16_t* x1      = (uint16_t*)(W + 50331648);
  uint16_t* comb_hi = (uint16_t*)(W + 0);           // alias qk (dead post-hash)
  uint16_t* comb_lo = (uint16_t*)(W + 16777216);

  hipLaunchKernelGGL(prep_kernel, dim3(9472), dim3(256), 0, stream,
                     X, Wv, Wo, x0, x1, wvT0, wvT1, woT_hi, woT_lo);
  hipLaunchKernelGGL(gemm_qk_kernel, dim3(128, 4), dim3(256), 0, stream,
                     X, Wqk, qk, qkhi, qklo, invn_g);
  hipLaunchKernelGGL(gemm_v_mfma_kernel, dim3(128, 4), dim3(512), 0, stream,
                     x0, x1, wvT0, wvT1, vhi);
  hipLaunchKernelGGL(hash_kernel, dim3(16, 32), dim3(256), 0, stream,
                     qk, rot, buckets);
  hipLaunchKernelGGL(sort_kernel, dim3(4, 32), dim3(256), 0, stream,
                     buckets, st);
  hipLaunchKernelGGL(attn_kernel, dim3(256, 32), dim3(256), 0, stream,
                     qkhi, qklo, vhi, invn_g, st, obuf, lse);
  hipLaunchKernelGGL(combine_kernel, dim3(32768), dim3(256), 0, stream,
                     obuf, lse, comb_hi, comb_lo);
  hipLaunchKernelGGL(gemm_out_kernel, dim3(128, 4), dim3(256), 0, stream,
                     comb_hi, comb_lo, woT_hi, woT_lo, bo, (float*)d_out);
}